// Round 1
// baseline (8889.069 us; speedup 1.0000x reference)
//
#include <hip/hip_runtime.h>
#include <hip/hip_bf16.h>
#include <math.h>

// Problem constants
#define BB 16
#define NN 80
#define DH_ 384
#define LDH 1664   // Hcat row stride: [H0 | H1 | H2 | fused] = 384*3 + 512

// ---------------------------------------------------------------------------
// Generic tiled f32 GEMM: C[r, o] = act(sum_k A[r, k] * W[o, k] + bias[o] (+C))
// BM=128, BN=64, BK=16, 256 threads, 8x4 per thread. R must be mult of 128,
// O mult of 64, K mult of 16 (all true for this problem).
// ---------------------------------------------------------------------------
__global__ __launch_bounds__(256)
void gemm_bias_act(const float* __restrict__ A, int lda,
                   const float* __restrict__ W, int ldw,
                   const float* __restrict__ bias,
                   float* __restrict__ C, int ldc,
                   int K, int act, int accum)
{
    __shared__ float As[16][132];
    __shared__ float Bs[16][68];
    const int tid = threadIdx.x;
    const int tx = tid & 15;    // output col quad [0,16)
    const int ty = tid >> 4;    // output row octet [0,16)
    const int r0 = blockIdx.y * 128;
    const int o0 = blockIdx.x * 64;

    float acc[8][4];
#pragma unroll
    for (int u = 0; u < 8; ++u)
#pragma unroll
        for (int v = 0; v < 4; ++v) acc[u][v] = 0.f;

    for (int kb = 0; kb < K; kb += 16) {
        // stage A tile (128x16) : 512 float4, 2 per thread
#pragma unroll
        for (int u = 0; u < 2; ++u) {
            int f = tid * 2 + u;        // 0..511
            int row = f >> 2;           // 0..127
            int kq = (f & 3) << 2;      // 0,4,8,12
            float4 v = *(const float4*)(A + (r0 + row) * lda + kb + kq);
            As[kq + 0][row] = v.x; As[kq + 1][row] = v.y;
            As[kq + 2][row] = v.z; As[kq + 3][row] = v.w;
        }
        {   // stage W tile (64x16): 256 float4, 1 per thread
            int row = tid >> 2;         // 0..63
            int kq = (tid & 3) << 2;
            float4 v = *(const float4*)(W + (o0 + row) * ldw + kb + kq);
            Bs[kq + 0][row] = v.x; Bs[kq + 1][row] = v.y;
            Bs[kq + 2][row] = v.z; Bs[kq + 3][row] = v.w;
        }
        __syncthreads();
#pragma unroll
        for (int k = 0; k < 16; ++k) {
            float4 a0 = *(const float4*)&As[k][ty * 8];
            float4 a1 = *(const float4*)&As[k][ty * 8 + 4];
            float4 bv = *(const float4*)&Bs[k][tx * 4];
            float av[8] = {a0.x, a0.y, a0.z, a0.w, a1.x, a1.y, a1.z, a1.w};
            float bb[4] = {bv.x, bv.y, bv.z, bv.w};
#pragma unroll
            for (int u = 0; u < 8; ++u)
#pragma unroll
                for (int v = 0; v < 4; ++v)
                    acc[u][v] = fmaf(av[u], bb[v], acc[u][v]);
        }
        __syncthreads();
    }
#pragma unroll
    for (int u = 0; u < 8; ++u) {
        int r = r0 + ty * 8 + u;
#pragma unroll
        for (int v = 0; v < 4; ++v) {
            int o = o0 + tx * 4 + v;
            float c = acc[u][v];
            if (bias) c += bias[o];
            if (accum) c += C[r * ldc + o];
            if (act == 1) c = fmaxf(c, 0.f);
            else if (act == 2) c = 1.f / (1.f + expf(-c));
            C[r * ldc + o] = c;
        }
    }
}

// c_ = sig(S1) * sig(S2) elementwise (sig already applied by GEMM epilogue)
__global__ void ew_mul(float* __restrict__ a, const float* __restrict__ b)
{
    int i = blockIdx.x * 256 + threadIdx.x;
    a[i] *= b[i];
}

// WrT[l][k][d] = (k<384 ? Wr0[l][d][k] : Wr1[l][d][k-384]) ; 2*768*384 elems
__global__ void trans_wr(const float* __restrict__ Wr0, const float* __restrict__ Wr1,
                         float* __restrict__ WrT)
{
    int idx = blockIdx.x * 256 + threadIdx.x;  // < 589824
    int l = idx / (768 * 384);
    int r = idx % (768 * 384);
    int k = r / 384, d = r % 384;
    float v = (k < 384) ? Wr0[l * 147456 + d * 384 + k]
                        : Wr1[l * 147456 + d * 384 + (k - 384)];
    WrT[idx] = v;
}

// WgT[l][k][o] = (o<1152 ? cwh[l][o][k] : pwi[l][o-1152][k]) ; 2*384*2304 elems
__global__ void trans_wg(const float* __restrict__ cwh, const float* __restrict__ pwi,
                         float* __restrict__ WgT)
{
    int idx = blockIdx.x * 256 + threadIdx.x;  // < 1769472
    int l = idx / (384 * 2304);
    int r = idx % (384 * 2304);
    int k = r / 2304, o = r % 2304;
    float v = (o < 1152) ? cwh[l * 442368 + o * 384 + k]
                         : pwi[l * 442368 + (o - 1152) * 384 + k];
    WgT[idx] = v;
}

// ---------------------------------------------------------------------------
// Sequential scan for one GAT/GRU layer. One workgroup per batch element.
// 576 threads (9 waves).
//   Hc      : Hcat base (read xi at column hin, write Hnew at column hout)
//   gPre    : [B*N][2304] = [ xi@cwi.T+cbi | xi@pwh.T+pbh ]
//   WrT     : [768][384]  (k<384: Wr0^T, else Wr1^T)
//   WgT     : [384][2304] (o<1152: cwh^T, else pwi^T)
// ---------------------------------------------------------------------------
__global__ __launch_bounds__(576)
void scan_layer(float* Hc, int hin, int hout,
                const float* __restrict__ gPre,
                const float* __restrict__ WrT,
                const float* __restrict__ WgT,
                const float* __restrict__ gatw,   // wq | wk (768)
                const float* __restrict__ gatb,   // scalar at [0]
                const int* __restrict__ adj,
                const int* __restrict__ smask,
                const float* __restrict__ cbh,
                const float* __restrict__ pbi)
{
    const int b = blockIdx.x;
    const int t = threadIdx.x;
    const int lane = t & 63;
    const int wave = t >> 6;

    __shared__ float kv[NN];         // k_j = h_j . wk (0 for unfilled rows)
    __shared__ float wv[NN];         // softmax weights
    __shared__ float sv[NN];         // s_mask row (float)
    __shared__ float xiS[DH_];
    __shared__ float aa[2 * DH_];    // a0 | a1
    __shared__ float Mpart[6][DH_];
    __shared__ float Mv[DH_];
    __shared__ float gout[2304];     // ghC (no bias) | giP (no bias)
    __shared__ float red[16];
    __shared__ float qS;

    if (t < NN) kv[t] = 0.f;
    const float gb = gatb[0];

    for (int i = 0; i < NN; ++i) {
        __syncthreads();  // kv/H writes of prev step visible
        const int rowi = b * NN + i;

        // ---- Phase 1: load xi, s row; partial q = xi . wq
        float qp = 0.f;
        if (t < DH_) {
            float x = Hc[rowi * LDH + hin + t];
            xiS[t] = x;
            qp = x * gatw[t];
        }
        if (t >= 448 && t < 448 + NN) sv[t - 448] = (float)smask[rowi * NN + (t - 448)];
#pragma unroll
        for (int m = 1; m < 64; m <<= 1) qp += __shfl_xor(qp, m);
        if (lane == 0) red[wave] = qp;
        __syncthreads();
        if (t == 0) qS = red[0] + red[1] + red[2] + red[3] + red[4] + red[5];
        __syncthreads();

        // ---- Phase 2: masked softmax over 80 positions (wave 0)
        if (t < 64) {
            float q = qS;
            float a0 = q + kv[t] + gb;
            if (!((t < i) && adj[rowi * NN + t])) a0 -= 1e30f;
            float a1 = -INFINITY;
            int j1 = t + 64;
            if (j1 < NN) {
                a1 = q + kv[j1] + gb;
                if (!((j1 < i) && adj[rowi * NN + j1])) a1 -= 1e30f;
            }
            float mx = fmaxf(a0, a1);
#pragma unroll
            for (int m = 1; m < 64; m <<= 1) mx = fmaxf(mx, __shfl_xor(mx, m));
            float e0 = expf(a0 - mx);
            float e1 = (j1 < NN) ? expf(a1 - mx) : 0.f;
            float ss = e0 + e1;
#pragma unroll
            for (int m = 1; m < 64; m <<= 1) ss += __shfl_xor(ss, m);
            float inv = 1.f / ss;
            wv[t] = e0 * inv;
            if (j1 < NN) wv[j1] = e1 * inv;
        }
        __syncthreads();

        // ---- Phase 3: a0[d] = sum_j w_j s_j h_jd ; a1[d] = sum_j w_j (1-s_j) h_jd
        if (t < DH_) {
            float A0 = 0.f, A1 = 0.f;
            const float* Hb = Hc + b * NN * LDH + hout + t;
#pragma unroll 4
            for (int j = 0; j < i; ++j) {
                float h = Hb[j * LDH];
                float tm = wv[j] * h;
                float sj = sv[j];
                A0 = fmaf(sj, tm, A0);
                A1 += tm - sj * tm;
            }
            aa[t] = A0;
            aa[DH_ + t] = A1;
        }
        __syncthreads();

        // ---- Phase 4: M = Wr0 @ a0 + Wr1 @ a1 (k-sliced partials)
        {
            int ks = t / 96;           // 0..5 -> k range [ks*128, ks*128+128)
            int dq = t % 96;           // output float4 index
            const float4* W4 = (const float4*)WrT;
            float4 acc = {0.f, 0.f, 0.f, 0.f};
            int k0 = ks * 128;
#pragma unroll 4
            for (int k = k0; k < k0 + 128; ++k) {
                float a = aa[k];
                float4 w = W4[k * 96 + dq];
                acc.x = fmaf(a, w.x, acc.x);
                acc.y = fmaf(a, w.y, acc.y);
                acc.z = fmaf(a, w.z, acc.z);
                acc.w = fmaf(a, w.w, acc.w);
            }
            *(float4*)&Mpart[ks][dq * 4] = acc;
        }
        __syncthreads();
        if (t < DH_)
            Mv[t] = Mpart[0][t] + Mpart[1][t] + Mpart[2][t] +
                    Mpart[3][t] + Mpart[4][t] + Mpart[5][t];
        __syncthreads();

        // ---- Phase 5: gout = [cwh @ M | pwi @ M] (2304 outputs, 4/thread)
        {
            const float4* W4 = (const float4*)WgT;
            float4 acc = {0.f, 0.f, 0.f, 0.f};
#pragma unroll 4
            for (int k = 0; k < DH_; ++k) {
                float m = Mv[k];
                float4 w = W4[k * 576 + t];
                acc.x = fmaf(m, w.x, acc.x);
                acc.y = fmaf(m, w.y, acc.y);
                acc.z = fmaf(m, w.z, acc.z);
                acc.w = fmaf(m, w.w, acc.w);
            }
            *(float4*)&gout[t * 4] = acc;
        }
        __syncthreads();

        // ---- Phase 6: GRU cells, Hnew, k_i partial
        float kp = 0.f;
        if (t < DH_) {
            const float* gp = gPre + rowi * 2304;
            float m = Mv[t];
            // C = gru(x=xi, h=M): gi precomputed, gh = M@cwh.T + cbh
            float gir = gp[t], giz = gp[DH_ + t], gin = gp[2 * DH_ + t];
            float ghr = gout[t] + cbh[t];
            float ghz = gout[DH_ + t] + cbh[DH_ + t];
            float ghn = gout[2 * DH_ + t] + cbh[2 * DH_ + t];
            float r = 1.f / (1.f + expf(-(gir + ghr)));
            float z = 1.f / (1.f + expf(-(giz + ghz)));
            float n = tanhf(gin + r * ghn);
            float Cc = (1.f - z) * n + z * m;
            // P = gru(x=M, h=xi): gi = M@pwi.T + pbi, gh precomputed
            float pir = gout[1152 + t] + pbi[t];
            float piz = gout[1152 + DH_ + t] + pbi[DH_ + t];
            float pin = gout[1152 + 2 * DH_ + t] + pbi[2 * DH_ + t];
            float phr = gp[1152 + t], phz = gp[1152 + DH_ + t], phn = gp[1152 + 2 * DH_ + t];
            float r2 = 1.f / (1.f + expf(-(pir + phr)));
            float z2 = 1.f / (1.f + expf(-(piz + phz)));
            float n2 = tanhf(pin + r2 * phn);
            float x = xiS[t];
            float Pp = (1.f - z2) * n2 + z2 * x;
            float h = Cc + Pp;
            Hc[rowi * LDH + hout + t] = h;
            kp = h * gatw[DH_ + t];   // wk
        }
#pragma unroll
        for (int m = 1; m < 64; m <<= 1) kp += __shfl_xor(kp, m);
        if (lane == 0) red[wave] = kp;
        __syncthreads();
        if (t == 0) kv[i] = red[0] + red[1] + red[2] + red[3] + red[4] + red[5];
        // loop-top __syncthreads makes kv[i] + H row i visible
    }
}

// logits (7) + log_softmax, one wave per row
__global__ __launch_bounds__(256)
void mlp_final(const float* __restrict__ h, const float* __restrict__ w2,
               const float* __restrict__ b2, float* __restrict__ out)
{
    int wave = threadIdx.x >> 6, lane = threadIdx.x & 63;
    int r = blockIdx.x * 4 + wave;   // < 1280
    float hreg[6];
#pragma unroll
    for (int m = 0; m < 6; ++m) hreg[m] = h[r * 384 + lane + 64 * m];
    float logit[7];
#pragma unroll
    for (int c = 0; c < 7; ++c) {
        float s = 0.f;
#pragma unroll
        for (int m = 0; m < 6; ++m)
            s = fmaf(hreg[m], w2[c * 384 + lane + 64 * m], s);
#pragma unroll
        for (int m = 1; m < 64; m <<= 1) s += __shfl_xor(s, m);
        logit[c] = s + b2[c];
    }
    float mx = logit[0];
#pragma unroll
    for (int c = 1; c < 7; ++c) mx = fmaxf(mx, logit[c]);
    float se = 0.f;
#pragma unroll
    for (int c = 0; c < 7; ++c) se += expf(logit[c] - mx);
    float lse = mx + logf(se);
    if (lane < 7) out[r * 7 + lane] = logit[lane] - lse;
}

extern "C" void kernel_launch(void* const* d_in, const int* in_sizes, int n_in,
                              void* d_out, int out_size, void* d_ws, size_t ws_size,
                              hipStream_t stream)
{
    const float* ftext = (const float*)d_in[0];
    const float* faud  = (const float*)d_in[1];
    const int*   adj   = (const int*)d_in[2];
    const int*   smask = (const int*)d_in[3];
    const float* U1    = (const float*)d_in[6];
    const float* U2    = (const float*)d_in[7];
    const float* Pw    = (const float*)d_in[8];
    const float* Pb    = (const float*)d_in[9];
    const float* V1    = (const float*)d_in[10];
    const float* V2    = (const float*)d_in[11];
    const float* fc1w  = (const float*)d_in[12];
    const float* fc1b  = (const float*)d_in[13];
    const float* gatw  = (const float*)d_in[14];
    const float* gatb  = (const float*)d_in[15];
    const float* Wr0   = (const float*)d_in[16];
    const float* Wr1   = (const float*)d_in[17];
    const float* cwi   = (const float*)d_in[18];
    const float* cwh   = (const float*)d_in[19];
    const float* cbi   = (const float*)d_in[20];
    const float* cbh   = (const float*)d_in[21];
    const float* pwi   = (const float*)d_in[22];
    const float* pwh   = (const float*)d_in[23];
    const float* pbi   = (const float*)d_in[24];
    const float* pbh   = (const float*)d_in[25];
    const float* w0    = (const float*)d_in[26];
    const float* b0    = (const float*)d_in[27];
    const float* w1    = (const float*)d_in[28];
    const float* b1    = (const float*)d_in[29];
    const float* w2    = (const float*)d_in[30];
    const float* b2    = (const float*)d_in[31];
    float* out = (float*)d_out;
    float* ws = (float*)d_ws;

    // workspace layout (f32 words)
    float* S1   = ws;                    // 1280*512
    float* S2   = S1 + 655360;           // 1280*512
    float* Hcat = S2 + 655360;           // 1280*1664
    float* gPre = Hcat + 2129920;        // 1280*2304
    float* WrT  = gPre + 2949120;        // 2*768*384
    float* WgT  = WrT + 589824;          // 2*384*2304

    dim3 blk(256);
    auto gemm = [&](const float* A, int lda, const float* W, int ldw,
                    const float* bias, float* C, int ldc, int K, int O,
                    int act, int accum) {
        dim3 grid(O / 64, 1280 / 128);
        gemm_bias_act<<<grid, blk, 0, stream>>>(A, lda, W, ldw, bias, C, ldc, K, act, accum);
    };

    // Front-end fusion
    gemm(ftext, 1024, U1, 1024, nullptr, S1, 512, 1024, 512, 2, 0);        // sig(text@U1^T)
    gemm(faud,  512,  U2, 512,  nullptr, S2, 512, 512,  512, 2, 0);        // sig(audio@U2^T)
    ew_mul<<<2560, 256, 0, stream>>>(S1, S2);                              // c_
    gemm(S1, 512, Pw, 512, Pb, Hcat + 1152, LDH, 512, 512, 0, 0);          // fused = c_@P^T + Pb
    gemm(ftext, 1024, V1, 1024, nullptr, Hcat + 1152, LDH, 1024, 512, 0, 1); // += text@V1^T
    gemm(faud, 512, V2, 512, nullptr, Hcat + 1152, LDH, 512, 512, 0, 1);   // += audio@V2^T
    gemm(Hcat + 1152, LDH, fc1w, 512, fc1b, Hcat, LDH, 512, 384, 1, 0);    // H0 = relu(...)

    // Pre-transposed recurrent weights
    trans_wr<<<2304, 256, 0, stream>>>(Wr0, Wr1, WrT);
    trans_wg<<<6912, 256, 0, stream>>>(cwh, pwi, WgT);

    // Two GAT/GRU layers
    for (int l = 0; l < 2; ++l) {
        gemm(Hcat + l * 384, LDH, cwi + l * 442368, 384, cbi + l * 1152,
             gPre, 2304, 384, 1152, 0, 0);                                 // giC
        gemm(Hcat + l * 384, LDH, pwh + l * 442368, 384, pbh + l * 1152,
             gPre + 1152, 2304, 384, 1152, 0, 0);                          // ghP
        scan_layer<<<16, 576, 0, stream>>>(Hcat, l * 384, (l + 1) * 384, gPre,
                                           WrT + l * 294912, WgT + l * 884736,
                                           gatw + l * 768, gatb + l, adj, smask,
                                           cbh + l * 1152, pbi + l * 1152);
    }

    // Back-end MLP + log_softmax
    gemm(Hcat, LDH, w0, LDH, b0, S2, 384, 1664, 384, 1, 0);                // h1 (reuse S2)
    gemm(S2, 384, w1, 384, b1, S1, 384, 384, 384, 1, 0);                   // h2 (reuse S1)
    mlp_final<<<320, 256, 0, stream>>>(S1, w2, b2, out);
}

// Round 2
// 3721.778 us; speedup vs baseline: 2.3884x; 2.3884x over previous
//
#include <hip/hip_runtime.h>
#include <hip/hip_bf16.h>
#include <math.h>

// Problem constants
#define BB 16
#define NN 80
#define DH_ 384
#define LDH 1664   // Hcat row stride: [H0 | H1 | H2 | fused] = 384*3 + 512

// ---------------------------------------------------------------------------
// Generic tiled f32 GEMM: C[r, o] = act(sum_k A[r, k] * W[o, k] + bias[o] (+C))
// ---------------------------------------------------------------------------
__global__ __launch_bounds__(256)
void gemm_bias_act(const float* __restrict__ A, int lda,
                   const float* __restrict__ W, int ldw,
                   const float* __restrict__ bias,
                   float* __restrict__ C, int ldc,
                   int K, int act, int accum)
{
    __shared__ float As[16][132];
    __shared__ float Bs[16][68];
    const int tid = threadIdx.x;
    const int tx = tid & 15;
    const int ty = tid >> 4;
    const int r0 = blockIdx.y * 128;
    const int o0 = blockIdx.x * 64;

    float acc[8][4];
#pragma unroll
    for (int u = 0; u < 8; ++u)
#pragma unroll
        for (int v = 0; v < 4; ++v) acc[u][v] = 0.f;

    for (int kb = 0; kb < K; kb += 16) {
#pragma unroll
        for (int u = 0; u < 2; ++u) {
            int f = tid * 2 + u;
            int row = f >> 2;
            int kq = (f & 3) << 2;
            float4 v = *(const float4*)(A + (r0 + row) * lda + kb + kq);
            As[kq + 0][row] = v.x; As[kq + 1][row] = v.y;
            As[kq + 2][row] = v.z; As[kq + 3][row] = v.w;
        }
        {
            int row = tid >> 2;
            int kq = (tid & 3) << 2;
            float4 v = *(const float4*)(W + (o0 + row) * ldw + kb + kq);
            Bs[kq + 0][row] = v.x; Bs[kq + 1][row] = v.y;
            Bs[kq + 2][row] = v.z; Bs[kq + 3][row] = v.w;
        }
        __syncthreads();
#pragma unroll
        for (int k = 0; k < 16; ++k) {
            float4 a0 = *(const float4*)&As[k][ty * 8];
            float4 a1 = *(const float4*)&As[k][ty * 8 + 4];
            float4 bv = *(const float4*)&Bs[k][tx * 4];
            float av[8] = {a0.x, a0.y, a0.z, a0.w, a1.x, a1.y, a1.z, a1.w};
            float bb[4] = {bv.x, bv.y, bv.z, bv.w};
#pragma unroll
            for (int u = 0; u < 8; ++u)
#pragma unroll
                for (int v = 0; v < 4; ++v)
                    acc[u][v] = fmaf(av[u], bb[v], acc[u][v]);
        }
        __syncthreads();
    }
#pragma unroll
    for (int u = 0; u < 8; ++u) {
        int r = r0 + ty * 8 + u;
#pragma unroll
        for (int v = 0; v < 4; ++v) {
            int o = o0 + tx * 4 + v;
            float c = acc[u][v];
            if (bias) c += bias[o];
            if (accum) c += C[r * ldc + o];
            if (act == 1) c = fmaxf(c, 0.f);
            else if (act == 2) c = 1.f / (1.f + expf(-c));
            C[r * ldc + o] = c;
        }
    }
}

__global__ void ew_mul(float* __restrict__ a, const float* __restrict__ b)
{
    int i = blockIdx.x * 256 + threadIdx.x;
    a[i] *= b[i];
}

// WrS[l][g][k=768][o=24]: slice g of [Wr0|Wr1] rows m=g*24+o, transposed k-major
__global__ void trans_wr2(const float* __restrict__ Wr0, const float* __restrict__ Wr1,
                          float* __restrict__ WrS)
{
    int idx = blockIdx.x * 256 + threadIdx.x;  // < 589824
    int l = idx / 294912;
    int r = idx % 294912;
    int g = r / 18432;
    int r2 = r % 18432;
    int k = r2 / 24, o = r2 % 24;
    int m = g * 24 + o;
    float v = (k < 384) ? Wr0[l * 147456 + m * 384 + k]
                        : Wr1[l * 147456 + m * 384 + (k - 384)];
    WrS[idx] = v;
}

// WgS[l][g][k=384][c=144]: c = idx6*24+o, idx6<3 -> cwh row idx6*384+(g*24+o),
// else pwi row (idx6-3)*384+(g*24+o); k-major.
__global__ void trans_wg2(const float* __restrict__ cwh, const float* __restrict__ pwi,
                          float* __restrict__ WgS)
{
    int idx = blockIdx.x * 256 + threadIdx.x;  // < 1769472
    int l = idx / 884736;
    int r = idx % 884736;
    int g = r / 55296;
    int r2 = r % 55296;
    int k = r2 / 144, c = r2 % 144;
    int idx6 = c / 24, o = c % 24;
    int d = g * 24 + o;
    float v = (idx6 < 3) ? cwh[l * 442368 + (idx6 * 384 + d) * 384 + k]
                         : pwi[l * 442368 + ((idx6 - 3) * 384 + d) * 384 + k];
    WgS[idx] = v;
}

// q[row] = dot(Hc[row, hin:hin+384], wq)
__global__ __launch_bounds__(256)
void qpre_k(const float* __restrict__ Hc, int hin, const float* __restrict__ wq,
            float* __restrict__ q)
{
    int wave = threadIdx.x >> 6, lane = threadIdx.x & 63;
    int row = blockIdx.x * 4 + wave;   // < 1280
    const float* hp = Hc + row * LDH + hin;
    float s = 0.f;
#pragma unroll
    for (int u = 0; u < 6; ++u) s = fmaf(hp[lane + 64 * u], wq[lane + 64 * u], s);
#pragma unroll
    for (int m = 1; m < 64; m <<= 1) s += __shfl_xor(s, m);
    if (lane == 0) q[row] = s;
}

// Cross-WG sync among the 16 WGs of one batch element. ctr is a per-(b,step,
// phase) counter pre-zeroed each launch. Release fence flushes this XCD's L2
// (writes visible at MALL); readers rely on first-touch-after-write lines or
// agent-scope atomic loads, so no acquire-invalidate is needed.
__device__ __forceinline__ void gsync(int* ctr)
{
    __syncthreads();
    if (threadIdx.x == 0) {
        __builtin_amdgcn_fence(__ATOMIC_RELEASE, "agent");
        __hip_atomic_fetch_add(ctr, 1, __ATOMIC_RELAXED, __HIP_MEMORY_SCOPE_AGENT);
        while (__hip_atomic_load(ctr, __ATOMIC_RELAXED, __HIP_MEMORY_SCOPE_AGENT) < 16)
            __builtin_amdgcn_s_sleep(1);
    }
    __syncthreads();
}

// ---------------------------------------------------------------------------
// Sliced sequential scan: 256 WGs = 16 b x 16 slices, 512 threads each.
// WG (b,g) owns M dims [g*24, g*24+24) and the matching 144 gate rows.
// ---------------------------------------------------------------------------
__global__ __launch_bounds__(512)
void scan2(float* Hc, int hin, int hout,
           const float* __restrict__ gPre,
           const float* __restrict__ WrS,    // layer slice base [16][768][24]
           const float* __restrict__ WgS,    // layer slice base [16][384][144]
           const float* __restrict__ qpre,   // [1280]
           const float* __restrict__ gatwl,  // [768] this layer (wq|wk)
           const float* __restrict__ gatbl,
           const int* __restrict__ adj,
           const int* __restrict__ smask,
           const float* __restrict__ cbh,
           const float* __restrict__ pbi,
           float* __restrict__ Mg,           // [16][384]
           float* __restrict__ kpart,        // [16][80][32] (128B rows)
           int* __restrict__ ctrM,
           int* __restrict__ ctrB)
{
    const int wg = blockIdx.x;
    const int b = wg >> 4, g = wg & 15;
    const int t = threadIdx.x;
    const float4* Wr4 = (const float4*)(WrS + g * 18432);   // [768][6] float4
    const float*  Wgp = WgS + g * 55296;                    // [384][144]

    __shared__ float kvS[NN], ws0[NN], ws1[NN];
    __shared__ float aa[768];
    __shared__ float Mpart[64][24];
    __shared__ float Mv[DH_];
    __shared__ float gpart[3][144];
    __shared__ float gs[144];
    __shared__ float karr[16];

    const float gb = gatbl[0];

    for (int i = 0; i < NN; ++i) {
        const int rowi = b * NN + i;

        // ---- kv[i-1] gather + masked softmax (skipped at i=0; M ends up 0)
        if (i > 0) {
            if (t < 16) karr[t] = kpart[(b * NN + i - 1) * 32 + t];
            __syncthreads();
            if (t == 0) {
                float s = 0.f;
#pragma unroll
                for (int u = 0; u < 16; ++u) s += karr[u];
                kvS[i - 1] = s;
            }
            __syncthreads();
            if (t < 64) {
                float q = qpre[rowi] + gb;
                int j0 = t, j1 = t + 64;
                float a0v = -1e30f, a1v = -1e30f;
                if (j0 < i && adj[rowi * NN + j0] != 0) a0v = q + kvS[j0];
                if (j1 < i && adj[rowi * NN + j1] != 0) a1v = q + kvS[j1];
                float mx = fmaxf(a0v, a1v);
#pragma unroll
                for (int m = 1; m < 64; m <<= 1) mx = fmaxf(mx, __shfl_xor(mx, m));
                float e0 = expf(a0v - mx);
                float e1 = (j1 < NN) ? expf(a1v - mx) : 0.f;
                float ss = e0 + e1;
#pragma unroll
                for (int m = 1; m < 64; m <<= 1) ss += __shfl_xor(ss, m);
                float inv = 1.f / ss;
                float w0 = e0 * inv;
                float s0 = (float)smask[rowi * NN + j0];
                ws0[j0] = w0 * s0;
                ws1[j0] = w0 - w0 * s0;
                if (j1 < NN) {
                    float w1 = e1 * inv;
                    float s1 = (float)smask[rowi * NN + j1];
                    ws0[j1] = w1 * s1;
                    ws1[j1] = w1 - w1 * s1;
                }
            }
        }
        __syncthreads();

        // ---- a0/a1: aa[d] = sum_j ws0[j] h_jd ; aa[384+d] = sum_j ws1[j] h_jd
        if (t < DH_) {
            float A0 = 0.f, A1 = 0.f;
            const float* Hb = Hc + b * NN * LDH + hout + t;
#pragma unroll 8
            for (int j = 0; j < i; ++j) {
                float h = Hb[j * LDH];
                A0 = fmaf(ws0[j], h, A0);
                A1 = fmaf(ws1[j], h, A1);
            }
            aa[t] = A0;
            aa[DH_ + t] = A1;
        }
        __syncthreads();

        // ---- M slice: 24 outputs, k-sliced over 64 chunks of 12
        if (t < 384) {
            int o4 = t % 6, kc = t / 6;
            float4 acc = {0.f, 0.f, 0.f, 0.f};
            int k0 = kc * 12;
#pragma unroll
            for (int k = k0; k < k0 + 12; ++k) {
                float a = aa[k];
                float4 w = Wr4[k * 6 + o4];
                acc.x = fmaf(a, w.x, acc.x);
                acc.y = fmaf(a, w.y, acc.y);
                acc.z = fmaf(a, w.z, acc.z);
                acc.w = fmaf(a, w.w, acc.w);
            }
            *(float4*)&Mpart[kc][o4 * 4] = acc;
        }
        __syncthreads();
        if (t < 24) {
            float s = 0.f;
#pragma unroll
            for (int kc = 0; kc < 64; ++kc) s += Mpart[kc][t];
            Mg[b * 384 + g * 24 + t] = s;
        }
        gsync(&ctrM[b * NN + i]);

        // ---- gather full M (agent-scope loads bypass stale L2 lines)
        if (t < 384)
            Mv[t] = __hip_atomic_load(&Mg[b * 384 + t], __ATOMIC_RELAXED,
                                      __HIP_MEMORY_SCOPE_AGENT);
        __syncthreads();

        // ---- gate slice: 144 outputs x 384 k, k split 3 ways
        if (t < 432) {
            int c = t % 144, kt = t / 144;
            float acc = 0.f;
            const float* wp = Wgp + kt * 128 * 144 + c;
            int kb = kt * 128;
#pragma unroll 8
            for (int k = 0; k < 128; ++k)
                acc = fmaf(Mv[kb + k], wp[k * 144], acc);
            gpart[kt][c] = acc;
        }
        __syncthreads();
        if (t < 144) gs[t] = gpart[0][t] + gpart[1][t] + gpart[2][t];
        __syncthreads();

        // ---- GRU cells for 24 dims + kpart
        if (t < 32) {
            float kp = 0.f;
            if (t < 24) {
                int dg = g * 24 + t;
                const float* gp = gPre + rowi * 2304;
                float m = Mv[dg];
                float gir = gp[dg], giz = gp[384 + dg], gin = gp[768 + dg];
                float ghr = gs[t] + cbh[dg];
                float ghz = gs[24 + t] + cbh[384 + dg];
                float ghn = gs[48 + t] + cbh[768 + dg];
                float r = 1.f / (1.f + expf(-(gir + ghr)));
                float z = 1.f / (1.f + expf(-(giz + ghz)));
                float n = tanhf(gin + r * ghn);
                float Cc = (1.f - z) * n + z * m;
                float pir = gs[72 + t] + pbi[dg];
                float piz = gs[96 + t] + pbi[384 + dg];
                float pin = gs[120 + t] + pbi[768 + dg];
                float phr = gp[1152 + dg], phz = gp[1536 + dg], phn = gp[1920 + dg];
                float r2 = 1.f / (1.f + expf(-(pir + phr)));
                float z2 = 1.f / (1.f + expf(-(piz + phz)));
                float n2 = tanhf(pin + r2 * phn);
                float x = Hc[rowi * LDH + hin + dg];
                float Pp = (1.f - z2) * n2 + z2 * x;
                float h = Cc + Pp;
                Hc[rowi * LDH + hout + dg] = h;
                kp = h * gatwl[384 + dg];
            }
#pragma unroll
            for (int m = 16; m >= 1; m >>= 1) kp += __shfl_down(kp, m);
            if (t == 0) kpart[(b * NN + i) * 32 + g] = kp;
        }
        gsync(&ctrB[b * NN + i]);
    }
}

// logits (7) + log_softmax, one wave per row
__global__ __launch_bounds__(256)
void mlp_final(const float* __restrict__ h, const float* __restrict__ w2,
               const float* __restrict__ b2, float* __restrict__ out)
{
    int wave = threadIdx.x >> 6, lane = threadIdx.x & 63;
    int r = blockIdx.x * 4 + wave;   // < 1280
    float hreg[6];
#pragma unroll
    for (int m = 0; m < 6; ++m) hreg[m] = h[r * 384 + lane + 64 * m];
    float logit[7];
#pragma unroll
    for (int c = 0; c < 7; ++c) {
        float s = 0.f;
#pragma unroll
        for (int m = 0; m < 6; ++m)
            s = fmaf(hreg[m], w2[c * 384 + lane + 64 * m], s);
#pragma unroll
        for (int m = 1; m < 64; m <<= 1) s += __shfl_xor(s, m);
        logit[c] = s + b2[c];
    }
    float mx = logit[0];
#pragma unroll
    for (int c = 1; c < 7; ++c) mx = fmaxf(mx, logit[c]);
    float se = 0.f;
#pragma unroll
    for (int c = 0; c < 7; ++c) se += expf(logit[c] - mx);
    float lse = mx + logf(se);
    if (lane < 7) out[r * 7 + lane] = logit[lane] - lse;
}

extern "C" void kernel_launch(void* const* d_in, const int* in_sizes, int n_in,
                              void* d_out, int out_size, void* d_ws, size_t ws_size,
                              hipStream_t stream)
{
    const float* ftext = (const float*)d_in[0];
    const float* faud  = (const float*)d_in[1];
    const int*   adj   = (const int*)d_in[2];
    const int*   smask = (const int*)d_in[3];
    const float* U1    = (const float*)d_in[6];
    const float* U2    = (const float*)d_in[7];
    const float* Pw    = (const float*)d_in[8];
    const float* Pb    = (const float*)d_in[9];
    const float* V1    = (const float*)d_in[10];
    const float* V2    = (const float*)d_in[11];
    const float* fc1w  = (const float*)d_in[12];
    const float* fc1b  = (const float*)d_in[13];
    const float* gatw  = (const float*)d_in[14];
    const float* gatb  = (const float*)d_in[15];
    const float* Wr0   = (const float*)d_in[16];
    const float* Wr1   = (const float*)d_in[17];
    const float* cwi   = (const float*)d_in[18];
    const float* cwh   = (const float*)d_in[19];
    const float* cbi   = (const float*)d_in[20];
    const float* cbh   = (const float*)d_in[21];
    const float* pwi   = (const float*)d_in[22];
    const float* pwh   = (const float*)d_in[23];
    const float* pbi   = (const float*)d_in[24];
    const float* pbh   = (const float*)d_in[25];
    const float* w0    = (const float*)d_in[26];
    const float* b0    = (const float*)d_in[27];
    const float* w1    = (const float*)d_in[28];
    const float* b1    = (const float*)d_in[29];
    const float* w2    = (const float*)d_in[30];
    const float* b2    = (const float*)d_in[31];
    float* out = (float*)d_out;
    float* ws = (float*)d_ws;

    // workspace layout (f32 words, all 128B-aligned)
    float* S1    = ws;                    // 655360
    float* S2    = S1 + 655360;           // 655360
    float* Hcat  = S2 + 655360;           // 1280*1664 = 2129920
    float* gPre  = Hcat + 2129920;        // 1280*2304 = 2949120
    float* WrT2  = gPre + 2949120;        // 589824
    float* Wg2   = WrT2 + 589824;         // 1769472
    float* qpreB = Wg2 + 1769472;         // 2560
    float* MgB   = qpreB + 2560;          // 6144
    float* kpB   = MgB + 6144;            // 2*16*80*32 = 81920
    int*   ctrB_ = (int*)(kpB + 81920);   // 5120 ints

    dim3 blk(256);
    auto gemm = [&](const float* A, int lda, const float* W, int ldw,
                    const float* bias, float* C, int ldc, int K, int O,
                    int act, int accum) {
        dim3 grid(O / 64, 1280 / 128);
        gemm_bias_act<<<grid, blk, 0, stream>>>(A, lda, W, ldw, bias, C, ldc, K, act, accum);
    };

    // Zero the sync counters (graph-capturable async memset)
    hipMemsetAsync(ctrB_, 0, 5120 * sizeof(int), stream);

    // Front-end fusion
    gemm(ftext, 1024, U1, 1024, nullptr, S1, 512, 1024, 512, 2, 0);
    gemm(faud,  512,  U2, 512,  nullptr, S2, 512, 512,  512, 2, 0);
    ew_mul<<<2560, 256, 0, stream>>>(S1, S2);
    gemm(S1, 512, Pw, 512, Pb, Hcat + 1152, LDH, 512, 512, 0, 0);
    gemm(ftext, 1024, V1, 1024, nullptr, Hcat + 1152, LDH, 1024, 512, 0, 1);
    gemm(faud, 512, V2, 512, nullptr, Hcat + 1152, LDH, 512, 512, 0, 1);
    gemm(Hcat + 1152, LDH, fc1w, 512, fc1b, Hcat, LDH, 512, 384, 1, 0);

    // Pre-transposed per-slice recurrent weights
    trans_wr2<<<2304, 256, 0, stream>>>(Wr0, Wr1, WrT2);
    trans_wg2<<<6912, 256, 0, stream>>>(cwh, pwi, Wg2);

    // Two GAT/GRU layers
    for (int l = 0; l < 2; ++l) {
        gemm(Hcat + l * 384, LDH, cwi + l * 442368, 384, cbi + l * 1152,
             gPre, 2304, 384, 1152, 0, 0);
        gemm(Hcat + l * 384, LDH, pwh + l * 442368, 384, pbh + l * 1152,
             gPre + 1152, 2304, 384, 1152, 0, 0);
        qpre_k<<<320, 256, 0, stream>>>(Hcat, l * 384, gatw + l * 768, qpreB + l * 1280);
        scan2<<<256, 512, 0, stream>>>(Hcat, l * 384, (l + 1) * 384, gPre,
                                       WrT2 + l * 294912, Wg2 + l * 884736,
                                       qpreB + l * 1280, gatw + l * 768, gatb + l,
                                       adj, smask, cbh + l * 1152, pbi + l * 1152,
                                       MgB, kpB + l * 40960,
                                       ctrB_ + l * 1280, ctrB_ + 2560 + l * 1280);
    }

    // Back-end MLP + log_softmax
    gemm(Hcat, LDH, w0, LDH, b0, S2, 384, 1664, 384, 1, 0);
    gemm(S2, 384, w1, 384, b1, S1, 384, 384, 384, 1, 0);
    mlp_final<<<320, 256, 0, stream>>>(S1, w2, b2, out);
}

// Round 3
// 2513.455 us; speedup vs baseline: 3.5366x; 1.4807x over previous
//
#include <hip/hip_runtime.h>
#include <hip/hip_bf16.h>
#include <math.h>

// Problem constants
#define BB 16
#define NN 80
#define DH_ 384
#define LDH 1664   // Hcat row stride: [H0 | H1 | H2 | fused] = 384*3 + 512

// ---------------------------------------------------------------------------
// Generic tiled f32 GEMM: C[r, o] = act(sum_k A[r, k] * W[o, k] + bias[o] (+C))
// ---------------------------------------------------------------------------
__global__ __launch_bounds__(256)
void gemm_bias_act(const float* __restrict__ A, int lda,
                   const float* __restrict__ W, int ldw,
                   const float* __restrict__ bias,
                   float* __restrict__ C, int ldc,
                   int K, int act, int accum)
{
    __shared__ float As[16][132];
    __shared__ float Bs[16][68];
    const int tid = threadIdx.x;
    const int tx = tid & 15;
    const int ty = tid >> 4;
    const int r0 = blockIdx.y * 128;
    const int o0 = blockIdx.x * 64;

    float acc[8][4];
#pragma unroll
    for (int u = 0; u < 8; ++u)
#pragma unroll
        for (int v = 0; v < 4; ++v) acc[u][v] = 0.f;

    for (int kb = 0; kb < K; kb += 16) {
#pragma unroll
        for (int u = 0; u < 2; ++u) {
            int f = tid * 2 + u;
            int row = f >> 2;
            int kq = (f & 3) << 2;
            float4 v = *(const float4*)(A + (r0 + row) * lda + kb + kq);
            As[kq + 0][row] = v.x; As[kq + 1][row] = v.y;
            As[kq + 2][row] = v.z; As[kq + 3][row] = v.w;
        }
        {
            int row = tid >> 2;
            int kq = (tid & 3) << 2;
            float4 v = *(const float4*)(W + (o0 + row) * ldw + kb + kq);
            Bs[kq + 0][row] = v.x; Bs[kq + 1][row] = v.y;
            Bs[kq + 2][row] = v.z; Bs[kq + 3][row] = v.w;
        }
        __syncthreads();
#pragma unroll
        for (int k = 0; k < 16; ++k) {
            float4 a0 = *(const float4*)&As[k][ty * 8];
            float4 a1 = *(const float4*)&As[k][ty * 8 + 4];
            float4 bv = *(const float4*)&Bs[k][tx * 4];
            float av[8] = {a0.x, a0.y, a0.z, a0.w, a1.x, a1.y, a1.z, a1.w};
            float bb[4] = {bv.x, bv.y, bv.z, bv.w};
#pragma unroll
            for (int u = 0; u < 8; ++u)
#pragma unroll
                for (int v = 0; v < 4; ++v)
                    acc[u][v] = fmaf(av[u], bb[v], acc[u][v]);
        }
        __syncthreads();
    }
#pragma unroll
    for (int u = 0; u < 8; ++u) {
        int r = r0 + ty * 8 + u;
#pragma unroll
        for (int v = 0; v < 4; ++v) {
            int o = o0 + tx * 4 + v;
            float c = acc[u][v];
            if (bias) c += bias[o];
            if (accum) c += C[r * ldc + o];
            if (act == 1) c = fmaxf(c, 0.f);
            else if (act == 2) c = 1.f / (1.f + expf(-c));
            C[r * ldc + o] = c;
        }
    }
}

__global__ void ew_mul(float* __restrict__ a, const float* __restrict__ b)
{
    int i = blockIdx.x * 256 + threadIdx.x;
    a[i] *= b[i];
}

// WgS[l][g][k=384][c=144]: c = idx6*24+o, idx6<3 -> cwh row idx6*384+(g*24+o),
// else pwi row (idx6-3)*384+(g*24+o); k-major.
__global__ void trans_wg2(const float* __restrict__ cwh, const float* __restrict__ pwi,
                          float* __restrict__ WgS)
{
    int idx = blockIdx.x * 256 + threadIdx.x;  // < 1769472
    int l = idx / 884736;
    int r = idx % 884736;
    int g = r / 55296;
    int r2 = r % 55296;
    int k = r2 / 144, c = r2 % 144;
    int idx6 = c / 24, o = c % 24;
    int d = g * 24 + o;
    float v = (idx6 < 3) ? cwh[l * 442368 + (idx6 * 384 + d) * 384 + k]
                         : pwi[l * 442368 + ((idx6 - 3) * 384 + d) * 384 + k];
    WgS[idx] = v;
}

// q[row] = dot(Hc[row, hin:hin+384], wq)
__global__ __launch_bounds__(256)
void qpre_k(const float* __restrict__ Hc, int hin, const float* __restrict__ wq,
            float* __restrict__ q)
{
    int wave = threadIdx.x >> 6, lane = threadIdx.x & 63;
    int row = blockIdx.x * 4 + wave;   // < 1280
    const float* hp = Hc + row * LDH + hin;
    float s = 0.f;
#pragma unroll
    for (int u = 0; u < 6; ++u) s = fmaf(hp[lane + 64 * u], wq[lane + 64 * u], s);
#pragma unroll
    for (int m = 1; m < 64; m <<= 1) s += __shfl_xor(s, m);
    if (lane == 0) q[row] = s;
}

// Lightweight cross-WG sync among 16 WGs. All cross-WG data uses agent-scope
// relaxed atomics (write-through to MALL); __syncthreads drains vmcnt per-wave,
// so the counter add is ordered after the data stores. No wbl2/inv fences.
__device__ __forceinline__ void gsync_lite(int* ctr)
{
    asm volatile("s_waitcnt vmcnt(0)" ::: "memory");
    __syncthreads();
    if (threadIdx.x == 0) {
        __hip_atomic_fetch_add(ctr, 1, __ATOMIC_RELAXED, __HIP_MEMORY_SCOPE_AGENT);
        while (__hip_atomic_load(ctr, __ATOMIC_RELAXED, __HIP_MEMORY_SCOPE_AGENT) < 16) {}
    }
    __syncthreads();
}

#define ALOADF(p)     __hip_atomic_load((p), __ATOMIC_RELAXED, __HIP_MEMORY_SCOPE_AGENT)
#define ASTOREF(p, v) __hip_atomic_store((p), (v), __ATOMIC_RELAXED, __HIP_MEMORY_SCOPE_AGENT)

// ---------------------------------------------------------------------------
// Sliced sequential scan v3: 256 WGs = 16 b x 16 slices, 512 threads.
// P-factorization: P0_j = Wr0 h_j, P1_j = Wr1 h_j computed once per row
// (48 dims/WG, LDS-cached) -> M slice = sum_j ws0[j]*P0 + ws1[j]*P1.
// ---------------------------------------------------------------------------
__global__ __launch_bounds__(512)
void scan3(float* Hc, int hin, int hout,
           const float* __restrict__ gPre,
           const float* __restrict__ Wr0l,   // [384][384] row-major (this layer)
           const float* __restrict__ Wr1l,
           const float* __restrict__ WgS,    // [16][384][144] slice k-major
           const float* __restrict__ qpre,   // [1280]
           const float* __restrict__ gatwl,  // [768] (wq|wk)
           const float* __restrict__ gatbl,
           const int* __restrict__ adj,
           const int* __restrict__ smask,
           const float* __restrict__ cbh,
           const float* __restrict__ pbi,
           float* __restrict__ Mg,           // [16][384]
           float* __restrict__ kpart,        // [16*80][32]
           int* __restrict__ ctrM,
           int* __restrict__ ctrB)
{
    const int wg = blockIdx.x;
    const int b = wg >> 4, g = wg & 15;
    const int t = threadIdx.x;
    const float* Wgp = WgS + g * 55296;

    extern __shared__ float dynpad[];   // residency ballast: forces 1 WG/CU
    __shared__ float Pc[80][50];        // P0 (cols 0..23) | P1 (cols 24..47)
    __shared__ float hrow[DH_];
    __shared__ float kvS[NN], ws0[NN], ws1[NN];
    __shared__ float Mv[DH_];
    __shared__ float gpart[3][144];
    __shared__ float gs[144];
    __shared__ float karr[16];

    // never-true runtime guard keeps dynpad alive without cost
    if (gatbl[0] > 1e30f) dynpad[t] = 0.f;

    const float gb = gatbl[0];

    for (int i = 0; i < NN; ++i) {
        const int rowi = b * NN + i;

        if (i > 0) {
            // ---- stage H[i-1] + kpart[i-1] from MALL
            if (t < DH_) hrow[t] = ALOADF(&Hc[(rowi - 1) * LDH + hout + t]);
            if (t < 16)  karr[t] = ALOADF(&kpart[(rowi - 1) * 32 + t]);
            __syncthreads();

            // ---- kv[i-1] + P-update for row i-1 (48 dims x 8 k-parts)
            if (t == 0) {
                float s = 0.f;
#pragma unroll
                for (int u = 0; u < 16; ++u) s += karr[u];
                kvS[i - 1] = s;
            }
            if (t < DH_) {
                int dl = t >> 3, part = t & 7;
                const float* wrow = (dl < 24) ? (Wr0l + (g * 24 + dl) * 384)
                                              : (Wr1l + (g * 24 + dl - 24) * 384);
                int k0 = part * 48;
                float p = 0.f;
#pragma unroll 8
                for (int k = 0; k < 48; ++k) p = fmaf(wrow[k0 + k], hrow[k0 + k], p);
#pragma unroll
                for (int m = 4; m >= 1; m >>= 1) p += __shfl_xor(p, m);
                if (part == 0) Pc[i - 1][dl] = p;
            }
            __syncthreads();

            // ---- masked softmax (wave 0)
            if (t < 64) {
                float q = qpre[rowi] + gb;
                int j0 = t, j1 = t + 64;
                float a0v = -1e30f, a1v = -1e30f;
                if (j0 < i && adj[rowi * NN + j0] != 0) a0v = q + kvS[j0];
                if (j1 < i && adj[rowi * NN + j1] != 0) a1v = q + kvS[j1];
                float mx = fmaxf(a0v, a1v);
#pragma unroll
                for (int m = 1; m < 64; m <<= 1) mx = fmaxf(mx, __shfl_xor(mx, m));
                float e0 = expf(a0v - mx);
                float e1 = (j1 < NN) ? expf(a1v - mx) : 0.f;
                float ss = e0 + e1;
#pragma unroll
                for (int m = 1; m < 64; m <<= 1) ss += __shfl_xor(ss, m);
                float inv = 1.f / ss;
                float w0 = e0 * inv;
                float s0 = (float)smask[rowi * NN + j0];
                ws0[j0] = w0 * s0;
                ws1[j0] = w0 - w0 * s0;
                if (j1 < NN) {
                    float w1 = e1 * inv;
                    float s1 = (float)smask[rowi * NN + j1];
                    ws0[j1] = w1 * s1;
                    ws1[j1] = w1 - w1 * s1;
                }
            }
            __syncthreads();

            // ---- M slice from LDS P-cache: 24 dims x 16-lane j-split
            if (t < DH_) {
                int dl = t >> 4, sub = t & 15;
                float acc = 0.f;
                for (int j = sub; j < i; j += 16)
                    acc += ws0[j] * Pc[j][dl] + ws1[j] * Pc[j][24 + dl];
#pragma unroll
                for (int m = 8; m >= 1; m >>= 1) acc += __shfl_xor(acc, m);
                if (sub == 0) ASTOREF(&Mg[b * 384 + g * 24 + dl], acc);
            }
            gsync_lite(&ctrM[rowi]);

            // ---- gather full M
            if (t < DH_) Mv[t] = ALOADF(&Mg[b * 384 + t]);
            __syncthreads();
        } else {
            if (t < DH_) Mv[t] = 0.f;
            __syncthreads();
        }

        // ---- gate slice: 144 outputs x 384 k, k split 3 ways (from L2)
        if (t < 432) {
            int c = t % 144, kt = t / 144;
            float acc = 0.f;
            const float* wp = Wgp + kt * 128 * 144 + c;
            int kb = kt * 128;
#pragma unroll 8
            for (int k = 0; k < 128; ++k)
                acc = fmaf(Mv[kb + k], wp[k * 144], acc);
            gpart[kt][c] = acc;
        }
        __syncthreads();
        if (t < 144) gs[t] = gpart[0][t] + gpart[1][t] + gpart[2][t];
        __syncthreads();

        // ---- GRU cells for 24 dims + kpart
        if (t < 32) {
            float kp = 0.f;
            if (t < 24) {
                int dg = g * 24 + t;
                const float* gp = gPre + rowi * 2304;
                float m = Mv[dg];
                float gir = gp[dg], giz = gp[384 + dg], gin = gp[768 + dg];
                float ghr = gs[t] + cbh[dg];
                float ghz = gs[24 + t] + cbh[384 + dg];
                float ghn = gs[48 + t] + cbh[768 + dg];
                float r = 1.f / (1.f + expf(-(gir + ghr)));
                float z = 1.f / (1.f + expf(-(giz + ghz)));
                float n = tanhf(gin + r * ghn);
                float Cc = (1.f - z) * n + z * m;
                float pir = gs[72 + t] + pbi[dg];
                float piz = gs[96 + t] + pbi[384 + dg];
                float pin = gs[120 + t] + pbi[768 + dg];
                float phr = gp[1152 + dg], phz = gp[1536 + dg], phn = gp[1920 + dg];
                float r2 = 1.f / (1.f + expf(-(pir + phr)));
                float z2 = 1.f / (1.f + expf(-(piz + phz)));
                float n2 = tanhf(pin + r2 * phn);
                float x = Hc[rowi * LDH + hin + dg];
                float Pp = (1.f - z2) * n2 + z2 * x;
                float h = Cc + Pp;
                ASTOREF(&Hc[rowi * LDH + hout + dg], h);
                kp = h * gatwl[384 + dg];
            }
#pragma unroll
            for (int m = 16; m >= 1; m >>= 1) kp += __shfl_down(kp, m);
            if (t == 0) ASTOREF(&kpart[rowi * 32 + g], kp);
        }
        gsync_lite(&ctrB[rowi]);
    }
}

// logits (7) + log_softmax, one wave per row
__global__ __launch_bounds__(256)
void mlp_final(const float* __restrict__ h, const float* __restrict__ w2,
               const float* __restrict__ b2, float* __restrict__ out)
{
    int wave = threadIdx.x >> 6, lane = threadIdx.x & 63;
    int r = blockIdx.x * 4 + wave;   // < 1280
    float hreg[6];
#pragma unroll
    for (int m = 0; m < 6; ++m) hreg[m] = h[r * 384 + lane + 64 * m];
    float logit[7];
#pragma unroll
    for (int c = 0; c < 7; ++c) {
        float s = 0.f;
#pragma unroll
        for (int m = 0; m < 6; ++m)
            s = fmaf(hreg[m], w2[c * 384 + lane + 64 * m], s);
#pragma unroll
        for (int m = 1; m < 64; m <<= 1) s += __shfl_xor(s, m);
        logit[c] = s + b2[c];
    }
    float mx = logit[0];
#pragma unroll
    for (int c = 1; c < 7; ++c) mx = fmaxf(mx, logit[c]);
    float se = 0.f;
#pragma unroll
    for (int c = 0; c < 7; ++c) se += expf(logit[c] - mx);
    float lse = mx + logf(se);
    if (lane < 7) out[r * 7 + lane] = logit[lane] - lse;
}

extern "C" void kernel_launch(void* const* d_in, const int* in_sizes, int n_in,
                              void* d_out, int out_size, void* d_ws, size_t ws_size,
                              hipStream_t stream)
{
    const float* ftext = (const float*)d_in[0];
    const float* faud  = (const float*)d_in[1];
    const int*   adj   = (const int*)d_in[2];
    const int*   smask = (const int*)d_in[3];
    const float* U1    = (const float*)d_in[6];
    const float* U2    = (const float*)d_in[7];
    const float* Pw    = (const float*)d_in[8];
    const float* Pb    = (const float*)d_in[9];
    const float* V1    = (const float*)d_in[10];
    const float* V2    = (const float*)d_in[11];
    const float* fc1w  = (const float*)d_in[12];
    const float* fc1b  = (const float*)d_in[13];
    const float* gatw  = (const float*)d_in[14];
    const float* gatb  = (const float*)d_in[15];
    const float* Wr0   = (const float*)d_in[16];
    const float* Wr1   = (const float*)d_in[17];
    const float* cwi   = (const float*)d_in[18];
    const float* cwh   = (const float*)d_in[19];
    const float* cbi   = (const float*)d_in[20];
    const float* cbh   = (const float*)d_in[21];
    const float* pwi   = (const float*)d_in[22];
    const float* pwh   = (const float*)d_in[23];
    const float* pbi   = (const float*)d_in[24];
    const float* pbh   = (const float*)d_in[25];
    const float* w0    = (const float*)d_in[26];
    const float* b0    = (const float*)d_in[27];
    const float* w1    = (const float*)d_in[28];
    const float* b1    = (const float*)d_in[29];
    const float* w2    = (const float*)d_in[30];
    const float* b2    = (const float*)d_in[31];
    float* out = (float*)d_out;
    float* ws = (float*)d_ws;

    // workspace layout (f32 words, 128B-aligned blocks)
    float* S1    = ws;                    // 655360
    float* S2    = S1 + 655360;           // 655360
    float* Hcat  = S2 + 655360;           // 1280*1664 = 2129920
    float* gPre  = Hcat + 2129920;        // 1280*2304 = 2949120
    float* Wg2   = gPre + 2949120;        // 1769472
    float* qpreB = Wg2 + 1769472;         // 2560
    float* MgB   = qpreB + 2560;          // 6144
    float* kpB   = MgB + 6144;            // 2*16*80*32 = 81920
    int*   ctrB_ = (int*)(kpB + 81920);   // 5120 ints

    dim3 blk(256);
    auto gemm = [&](const float* A, int lda, const float* W, int ldw,
                    const float* bias, float* C, int ldc, int K, int O,
                    int act, int accum) {
        dim3 grid(O / 64, 1280 / 128);
        gemm_bias_act<<<grid, blk, 0, stream>>>(A, lda, W, ldw, bias, C, ldc, K, act, accum);
    };

    // Zero the sync counters (graph-capturable async memset)
    hipMemsetAsync(ctrB_, 0, 5120 * sizeof(int), stream);

    // Front-end fusion
    gemm(ftext, 1024, U1, 1024, nullptr, S1, 512, 1024, 512, 2, 0);
    gemm(faud,  512,  U2, 512,  nullptr, S2, 512, 512,  512, 2, 0);
    ew_mul<<<2560, 256, 0, stream>>>(S1, S2);
    gemm(S1, 512, Pw, 512, Pb, Hcat + 1152, LDH, 512, 512, 0, 0);
    gemm(ftext, 1024, V1, 1024, nullptr, Hcat + 1152, LDH, 1024, 512, 0, 1);
    gemm(faud, 512, V2, 512, nullptr, Hcat + 1152, LDH, 512, 512, 0, 1);
    gemm(Hcat + 1152, LDH, fc1w, 512, fc1b, Hcat, LDH, 512, 384, 1, 0);

    // Pre-transposed per-slice gate weights
    trans_wg2<<<6912, 256, 0, stream>>>(cwh, pwi, Wg2);

    // Two GAT/GRU layers
    for (int l = 0; l < 2; ++l) {
        gemm(Hcat + l * 384, LDH, cwi + l * 442368, 384, cbi + l * 1152,
             gPre, 2304, 384, 1152, 0, 0);
        gemm(Hcat + l * 384, LDH, pwh + l * 442368, 384, pbh + l * 1152,
             gPre + 1152, 2304, 384, 1152, 0, 0);
        qpre_k<<<320, 256, 0, stream>>>(Hcat, l * 384, gatw + l * 768, qpreB + l * 1280);
        scan3<<<256, 512, 65536, stream>>>(Hcat, l * 384, (l + 1) * 384, gPre,
                                           Wr0 + l * 147456, Wr1 + l * 147456,
                                           Wg2 + l * 884736,
                                           qpreB + l * 1280, gatw + l * 768, gatb + l,
                                           adj, smask, cbh + l * 1152, pbi + l * 1152,
                                           MgB, kpB + l * 40960,
                                           ctrB_ + l * 1280, ctrB_ + 2560 + l * 1280);
    }

    // Back-end MLP + log_softmax
    gemm(Hcat, LDH, w0, LDH, b0, S2, 384, 1664, 384, 1, 0);
    gemm(S2, 384, w1, 384, b1, S1, 384, 384, 384, 1, 0);
    mlp_final<<<320, 256, 0, stream>>>(S1, w2, b2, out);
}

// Round 4
// 2142.580 us; speedup vs baseline: 4.1488x; 1.1731x over previous
//
#include <hip/hip_runtime.h>
#include <hip/hip_bf16.h>
#include <math.h>

// Problem constants
#define BB 16
#define NN 80
#define DH_ 384
#define LDH 1664   // Hcat row stride: [H0 | H1 | H2 | fused] = 384*3 + 512

typedef unsigned int uint;

// ---------------------------------------------------------------------------
// Generic tiled f32 GEMM: C[r, o] = act(sum_k A[r, k] * W[o, k] + bias[o] (+C))
// ---------------------------------------------------------------------------
__global__ __launch_bounds__(256)
void gemm_bias_act(const float* __restrict__ A, int lda,
                   const float* __restrict__ W, int ldw,
                   const float* __restrict__ bias,
                   float* __restrict__ C, int ldc,
                   int K, int act, int accum)
{
    __shared__ float As[16][132];
    __shared__ float Bs[16][68];
    const int tid = threadIdx.x;
    const int tx = tid & 15;
    const int ty = tid >> 4;
    const int r0 = blockIdx.y * 128;
    const int o0 = blockIdx.x * 64;

    float acc[8][4];
#pragma unroll
    for (int u = 0; u < 8; ++u)
#pragma unroll
        for (int v = 0; v < 4; ++v) acc[u][v] = 0.f;

    for (int kb = 0; kb < K; kb += 16) {
#pragma unroll
        for (int u = 0; u < 2; ++u) {
            int f = tid * 2 + u;
            int row = f >> 2;
            int kq = (f & 3) << 2;
            float4 v = *(const float4*)(A + (r0 + row) * lda + kb + kq);
            As[kq + 0][row] = v.x; As[kq + 1][row] = v.y;
            As[kq + 2][row] = v.z; As[kq + 3][row] = v.w;
        }
        {
            int row = tid >> 2;
            int kq = (tid & 3) << 2;
            float4 v = *(const float4*)(W + (o0 + row) * ldw + kb + kq);
            Bs[kq + 0][row] = v.x; Bs[kq + 1][row] = v.y;
            Bs[kq + 2][row] = v.z; Bs[kq + 3][row] = v.w;
        }
        __syncthreads();
#pragma unroll
        for (int k = 0; k < 16; ++k) {
            float4 a0 = *(const float4*)&As[k][ty * 8];
            float4 a1 = *(const float4*)&As[k][ty * 8 + 4];
            float4 bv = *(const float4*)&Bs[k][tx * 4];
            float av[8] = {a0.x, a0.y, a0.z, a0.w, a1.x, a1.y, a1.z, a1.w};
            float bb[4] = {bv.x, bv.y, bv.z, bv.w};
#pragma unroll
            for (int u = 0; u < 8; ++u)
#pragma unroll
                for (int v = 0; v < 4; ++v)
                    acc[u][v] = fmaf(av[u], bb[v], acc[u][v]);
        }
        __syncthreads();
    }
#pragma unroll
    for (int u = 0; u < 8; ++u) {
        int r = r0 + ty * 8 + u;
#pragma unroll
        for (int v = 0; v < 4; ++v) {
            int o = o0 + tx * 4 + v;
            float c = acc[u][v];
            if (bias) c += bias[o];
            if (accum) c += C[r * ldc + o];
            if (act == 1) c = fmaxf(c, 0.f);
            else if (act == 2) c = 1.f / (1.f + expf(-c));
            C[r * ldc + o] = c;
        }
    }
}

__global__ void ew_mul(float* __restrict__ a, const float* __restrict__ b)
{
    int i = blockIdx.x * 256 + threadIdx.x;
    a[i] *= b[i];
}

// ---- bf16 pack helpers (RNE) ----
__device__ __forceinline__ uint packbf(float lo, float hi)
{
    uint a = __float_as_uint(lo);
    a = (a + 0x7fffu + ((a >> 16) & 1u)) >> 16;
    uint b = __float_as_uint(hi);
    b = (b + 0x7fffu + ((b >> 16) & 1u)) & 0xffff0000u;
    return a | b;
}
__device__ __forceinline__ float bflo(uint u) { return __uint_as_float(u << 16); }
__device__ __forceinline__ float bfhi(uint u) { return __uint_as_float(u & 0xffff0000u); }

// WgPk[l][g][k=384][cp=72]: packed bf16 pair for gate cols c=2cp (lo), 2cp+1 (hi).
// c = idx6*24+o; idx6<3 -> cwh row idx6*384+(g*24+o), else pwi row (idx6-3)*384+(g*24+o).
__global__ void trans_wg3(const float* __restrict__ cwh, const float* __restrict__ pwi,
                          uint* __restrict__ WgPk)
{
    int idx = blockIdx.x * 256 + threadIdx.x;  // < 884736
    int l = idx / 442368;
    int r = idx % 442368;
    int g = r / 27648;
    int r2 = r % 27648;
    int k = r2 / 72, cp = r2 % 72;
    float v[2];
#pragma unroll
    for (int u = 0; u < 2; ++u) {
        int c = 2 * cp + u;
        int idx6 = c / 24, o = c % 24, d = g * 24 + o;
        v[u] = (idx6 < 3) ? cwh[l * 442368 + (idx6 * 384 + d) * 384 + k]
                          : pwi[l * 442368 + ((idx6 - 3) * 384 + d) * 384 + k];
    }
    WgPk[idx] = packbf(v[0], v[1]);
}

// WrPk[l][g][k=384][dl=24]: packed bf16 (Wr0[g*24+dl][k] lo, Wr1[...][k] hi)
__global__ void trans_wr3(const float* __restrict__ Wr0, const float* __restrict__ Wr1,
                          uint* __restrict__ WrPk)
{
    int idx = blockIdx.x * 256 + threadIdx.x;  // < 294912
    int l = idx / 147456;
    int r = idx % 147456;
    int g = r / 9216;
    int r2 = r % 9216;
    int k = r2 / 24, dl = r2 % 24;
    int row = g * 24 + dl;
    float w0 = Wr0[l * 147456 + row * 384 + k];
    float w1 = Wr1[l * 147456 + row * 384 + k];
    WrPk[idx] = packbf(w0, w1);
}

// q[row] = dot(Hc[row, hin:hin+384], wq)
__global__ __launch_bounds__(256)
void qpre_k(const float* __restrict__ Hc, int hin, const float* __restrict__ wq,
            float* __restrict__ q)
{
    int wave = threadIdx.x >> 6, lane = threadIdx.x & 63;
    int row = blockIdx.x * 4 + wave;   // < 1280
    const float* hp = Hc + row * LDH + hin;
    float s = 0.f;
#pragma unroll
    for (int u = 0; u < 6; ++u) s = fmaf(hp[lane + 64 * u], wq[lane + 64 * u], s);
#pragma unroll
    for (int m = 1; m < 64; m <<= 1) s += __shfl_xor(s, m);
    if (lane == 0) q[row] = s;
}

// Lightweight cross-WG sync among 16 WGs (agent-scope atomics, no L2 flush).
__device__ __forceinline__ void gsync_lite(int* ctr)
{
    asm volatile("s_waitcnt vmcnt(0)" ::: "memory");
    __syncthreads();
    if (threadIdx.x == 0) {
        __hip_atomic_fetch_add(ctr, 1, __ATOMIC_RELAXED, __HIP_MEMORY_SCOPE_AGENT);
        while (__hip_atomic_load(ctr, __ATOMIC_RELAXED, __HIP_MEMORY_SCOPE_AGENT) < 16) {}
    }
    __syncthreads();
}

#define ALOADF(p)     __hip_atomic_load((p), __ATOMIC_RELAXED, __HIP_MEMORY_SCOPE_AGENT)
#define ASTOREF(p, v) __hip_atomic_store((p), (v), __ATOMIC_RELAXED, __HIP_MEMORY_SCOPE_AGENT)

// ---------------------------------------------------------------------------
// Sliced scan v4: 256 WGs = 16 b x 16 slices, 512 threads, weights in LDS (bf16).
// ---------------------------------------------------------------------------
__global__ __launch_bounds__(512)
void scan4(float* Hc, int hin, int hout,
           const float* __restrict__ gPre,
           const uint* __restrict__ WrPkl,   // [16][384][24] this layer
           const uint* __restrict__ WgPkl,   // [16][384][72] this layer
           const float* __restrict__ qpre,
           const float* __restrict__ gatwl,
           const float* __restrict__ gatbl,
           const int* __restrict__ adj,
           const int* __restrict__ smask,
           const float* __restrict__ cbh,
           const float* __restrict__ pbi,
           float* __restrict__ Mg,           // [16][384]
           float* __restrict__ kpart,        // [16*80][32]
           int* __restrict__ ctrM,
           int* __restrict__ ctrB)
{
    const int wg = blockIdx.x;
    const int b = wg >> 4, g = wg & 15;
    const int t = threadIdx.x;

    extern __shared__ uint WgL[];    // [384][72] packed, 110592 B dynamic
    __shared__ uint WrL[9216];       // [384][24] packed
    __shared__ uint Pc16[NN][24];    // packed (P0 lo, P1 hi)
    __shared__ float kvS[NN];
    __shared__ float2 ws01[NN];
    __shared__ float Mv[DH_];
    __shared__ float gs[144];
    __shared__ float karr[16];
    __shared__ float unionBuf[864];  // hrow[384] (stage/P) | gpart[6][144] (gate)
    float* hrow = unionBuf;
    float* gpart = unionBuf;

    {   // preload packed weights into LDS (once)
        const uint* src = WgPkl + g * 27648;
        for (int idx = t; idx < 27648; idx += 512) WgL[idx] = src[idx];
        const uint* src2 = WrPkl + g * 9216;
        for (int idx = t; idx < 9216; idx += 512) WrL[idx] = src2[idx];
    }
    __syncthreads();

    const float gb = gatbl[0];

    for (int i = 0; i < NN; ++i) {
        const int rowi = b * NN + i;

        if (i > 0) {
            // ---- stage H[i-1] + kpart[i-1] (intra-kernel cross-WG -> atomics)
            if (t < DH_) hrow[t] = ALOADF(&Hc[(rowi - 1) * LDH + hout + t]);
            if (t >= 384 && t < 400) karr[t - 384] = ALOADF(&kpart[(rowi - 1) * 32 + (t - 384)]);
            __syncthreads();

            // ---- kv[i-1] scalar + P-update for row i-1 (from LDS bf16)
            if (t == 384) {
                float s = 0.f;
#pragma unroll
                for (int u = 0; u < 16; ++u) s += karr[u];
                kvS[i - 1] = s;
            }
            if (t < DH_) {
                int dl0 = t >> 4, sub = t & 15, part = sub & 7, half = sub >> 3;
                float acc = 0.f;
#pragma unroll 8
                for (int m = 0; m < 48; ++m) {
                    int k = part + 8 * m;
                    uint u = WrL[k * 24 + dl0];
                    float w = half ? bfhi(u) : bflo(u);
                    acc = fmaf(w, hrow[k], acc);
                }
                acc += __shfl_xor(acc, 1);
                acc += __shfl_xor(acc, 2);
                acc += __shfl_xor(acc, 4);
                float other = __shfl_xor(acc, 8);
                if (sub == 0) Pc16[i - 1][dl0] = packbf(acc, other);
            }
            __syncthreads();

            // ---- masked softmax (wave 0)
            if (t < 64) {
                float q = qpre[rowi] + gb;
                int j0 = t, j1 = t + 64;
                float a0v = -1e30f, a1v = -1e30f;
                if (j0 < i && adj[rowi * NN + j0] != 0) a0v = q + kvS[j0];
                if (j1 < i && adj[rowi * NN + j1] != 0) a1v = q + kvS[j1];
                float mx = fmaxf(a0v, a1v);
#pragma unroll
                for (int m = 1; m < 64; m <<= 1) mx = fmaxf(mx, __shfl_xor(mx, m));
                float e0 = expf(a0v - mx);
                float e1 = (j1 < NN) ? expf(a1v - mx) : 0.f;
                float ss = e0 + e1;
#pragma unroll
                for (int m = 1; m < 64; m <<= 1) ss += __shfl_xor(ss, m);
                float inv = 1.f / ss;
                float w0 = e0 * inv;
                float s0 = (float)smask[rowi * NN + j0];
                ws01[j0] = make_float2(w0 * s0, w0 - w0 * s0);
                if (j1 < NN) {
                    float w1 = e1 * inv;
                    float s1 = (float)smask[rowi * NN + j1];
                    ws01[j1] = make_float2(w1 * s1, w1 - w1 * s1);
                }
            }
            __syncthreads();

            // ---- M slice from packed P-cache
            if (t < DH_) {
                int dl0 = t >> 4, sub = t & 15;
                float acc = 0.f;
                for (int j = sub; j < i; j += 16) {
                    uint u = Pc16[j][dl0];
                    float2 w = ws01[j];
                    acc = fmaf(w.x, bflo(u), acc);
                    acc = fmaf(w.y, bfhi(u), acc);
                }
                acc += __shfl_xor(acc, 1);
                acc += __shfl_xor(acc, 2);
                acc += __shfl_xor(acc, 4);
                acc += __shfl_xor(acc, 8);
                if (sub == 0) ASTOREF(&Mg[b * 384 + g * 24 + dl0], acc);
            }
            gsync_lite(&ctrM[rowi]);

            if (t < DH_) Mv[t] = ALOADF(&Mg[b * 384 + t]);
            __syncthreads();
        } else {
            if (t < DH_) Mv[t] = 0.f;
            __syncthreads();
        }

        // ---- gate slice from LDS bf16: 144 outputs = 72 pairs x 6 k-chunks
        if (t < 432) {
            int cp = t % 72, kt = t / 72;
            int kbase = kt * 64;
            float a0 = 0.f, a1 = 0.f;
#pragma unroll 8
            for (int kk = 0; kk < 64; ++kk) {
                uint u = WgL[(kbase + kk) * 72 + cp];
                float m = Mv[kbase + kk];
                a0 = fmaf(bflo(u), m, a0);
                a1 = fmaf(bfhi(u), m, a1);
            }
            gpart[kt * 144 + 2 * cp] = a0;
            gpart[kt * 144 + 2 * cp + 1] = a1;
        }
        __syncthreads();
        if (t < 144) {
            float s = 0.f;
#pragma unroll
            for (int kt = 0; kt < 6; ++kt) s += gpart[kt * 144 + t];
            gs[t] = s;
        }
        __syncthreads();

        // ---- GRU cells for 24 dims + kpart
        if (t < 32) {
            float kp = 0.f;
            if (t < 24) {
                int dg = g * 24 + t;
                const float* gp = gPre + rowi * 2304;
                float m = Mv[dg];
                float gir = gp[dg], giz = gp[384 + dg], gin = gp[768 + dg];
                float ghr = gs[t] + cbh[dg];
                float ghz = gs[24 + t] + cbh[384 + dg];
                float ghn = gs[48 + t] + cbh[768 + dg];
                float r = 1.f / (1.f + expf(-(gir + ghr)));
                float z = 1.f / (1.f + expf(-(giz + ghz)));
                float n = tanhf(gin + r * ghn);
                float Cc = (1.f - z) * n + z * m;
                float pir = gs[72 + t] + pbi[dg];
                float piz = gs[96 + t] + pbi[384 + dg];
                float pin = gs[120 + t] + pbi[768 + dg];
                float phr = gp[1152 + dg], phz = gp[1536 + dg], phn = gp[1920 + dg];
                float r2 = 1.f / (1.f + expf(-(pir + phr)));
                float z2 = 1.f / (1.f + expf(-(piz + phz)));
                float n2 = tanhf(pin + r2 * phn);
                float x = Hc[rowi * LDH + hin + dg];
                float Pp = (1.f - z2) * n2 + z2 * x;
                float h = Cc + Pp;
                ASTOREF(&Hc[rowi * LDH + hout + dg], h);
                kp = h * gatwl[384 + dg];
            }
#pragma unroll
            for (int m = 16; m >= 1; m >>= 1) kp += __shfl_down(kp, m);
            if (t == 0) ASTOREF(&kpart[rowi * 32 + g], kp);
        }
        gsync_lite(&ctrB[rowi]);
    }
}

// logits (7) + log_softmax, one wave per row
__global__ __launch_bounds__(256)
void mlp_final(const float* __restrict__ h, const float* __restrict__ w2,
               const float* __restrict__ b2, float* __restrict__ out)
{
    int wave = threadIdx.x >> 6, lane = threadIdx.x & 63;
    int r = blockIdx.x * 4 + wave;   // < 1280
    float hreg[6];
#pragma unroll
    for (int m = 0; m < 6; ++m) hreg[m] = h[r * 384 + lane + 64 * m];
    float logit[7];
#pragma unroll
    for (int c = 0; c < 7; ++c) {
        float s = 0.f;
#pragma unroll
        for (int m = 0; m < 6; ++m)
            s = fmaf(hreg[m], w2[c * 384 + lane + 64 * m], s);
#pragma unroll
        for (int m = 1; m < 64; m <<= 1) s += __shfl_xor(s, m);
        logit[c] = s + b2[c];
    }
    float mx = logit[0];
#pragma unroll
    for (int c = 1; c < 7; ++c) mx = fmaxf(mx, logit[c]);
    float se = 0.f;
#pragma unroll
    for (int c = 0; c < 7; ++c) se += expf(logit[c] - mx);
    float lse = mx + logf(se);
    if (lane < 7) out[r * 7 + lane] = logit[lane] - lse;
}

extern "C" void kernel_launch(void* const* d_in, const int* in_sizes, int n_in,
                              void* d_out, int out_size, void* d_ws, size_t ws_size,
                              hipStream_t stream)
{
    const float* ftext = (const float*)d_in[0];
    const float* faud  = (const float*)d_in[1];
    const int*   adj   = (const int*)d_in[2];
    const int*   smask = (const int*)d_in[3];
    const float* U1    = (const float*)d_in[6];
    const float* U2    = (const float*)d_in[7];
    const float* Pw    = (const float*)d_in[8];
    const float* Pb    = (const float*)d_in[9];
    const float* V1    = (const float*)d_in[10];
    const float* V2    = (const float*)d_in[11];
    const float* fc1w  = (const float*)d_in[12];
    const float* fc1b  = (const float*)d_in[13];
    const float* gatw  = (const float*)d_in[14];
    const float* gatb  = (const float*)d_in[15];
    const float* Wr0   = (const float*)d_in[16];
    const float* Wr1   = (const float*)d_in[17];
    const float* cwi   = (const float*)d_in[18];
    const float* cwh   = (const float*)d_in[19];
    const float* cbi   = (const float*)d_in[20];
    const float* cbh   = (const float*)d_in[21];
    const float* pwi   = (const float*)d_in[22];
    const float* pwh   = (const float*)d_in[23];
    const float* pbi   = (const float*)d_in[24];
    const float* pbh   = (const float*)d_in[25];
    const float* w0    = (const float*)d_in[26];
    const float* b0    = (const float*)d_in[27];
    const float* w1    = (const float*)d_in[28];
    const float* b1    = (const float*)d_in[29];
    const float* w2    = (const float*)d_in[30];
    const float* b2    = (const float*)d_in[31];
    float* out = (float*)d_out;
    float* ws = (float*)d_ws;

    // workspace layout (f32 words, 128B-aligned blocks)
    float* S1    = ws;                    // 655360
    float* S2    = S1 + 655360;           // 655360
    float* Hcat  = S2 + 655360;           // 2129920
    float* gPre  = Hcat + 2129920;        // 2949120
    uint*  WgPk  = (uint*)(gPre + 2949120); // 884736
    uint*  WrPk  = WgPk + 884736;         // 294912
    float* qpreB = (float*)(WrPk + 294912); // 2560
    float* MgB   = qpreB + 2560;          // 6144
    float* kpB   = MgB + 6144;            // 81920
    int*   ctrB_ = (int*)(kpB + 81920);   // 5120 ints

    dim3 blk(256);
    auto gemm = [&](const float* A, int lda, const float* W, int ldw,
                    const float* bias, float* C, int ldc, int K, int O,
                    int act, int accum) {
        dim3 grid(O / 64, 1280 / 128);
        gemm_bias_act<<<grid, blk, 0, stream>>>(A, lda, W, ldw, bias, C, ldc, K, act, accum);
    };

    hipMemsetAsync(ctrB_, 0, 5120 * sizeof(int), stream);

    // Front-end fusion
    gemm(ftext, 1024, U1, 1024, nullptr, S1, 512, 1024, 512, 2, 0);
    gemm(faud,  512,  U2, 512,  nullptr, S2, 512, 512,  512, 2, 0);
    ew_mul<<<2560, 256, 0, stream>>>(S1, S2);
    gemm(S1, 512, Pw, 512, Pb, Hcat + 1152, LDH, 512, 512, 0, 0);
    gemm(ftext, 1024, V1, 1024, nullptr, Hcat + 1152, LDH, 1024, 512, 0, 1);
    gemm(faud, 512, V2, 512, nullptr, Hcat + 1152, LDH, 512, 512, 0, 1);
    gemm(Hcat + 1152, LDH, fc1w, 512, fc1b, Hcat, LDH, 512, 384, 1, 0);

    // Packed bf16 recurrent weights
    trans_wg3<<<3456, 256, 0, stream>>>(cwh, pwi, WgPk);
    trans_wr3<<<1152, 256, 0, stream>>>(Wr0, Wr1, WrPk);

    // Two GAT/GRU layers
    for (int l = 0; l < 2; ++l) {
        gemm(Hcat + l * 384, LDH, cwi + l * 442368, 384, cbi + l * 1152,
             gPre, 2304, 384, 1152, 0, 0);
        gemm(Hcat + l * 384, LDH, pwh + l * 442368, 384, pbh + l * 1152,
             gPre + 1152, 2304, 384, 1152, 0, 0);
        qpre_k<<<320, 256, 0, stream>>>(Hcat, l * 384, gatw + l * 768, qpreB + l * 1280);
        scan4<<<256, 512, 110592, stream>>>(Hcat, l * 384, (l + 1) * 384, gPre,
                                            WrPk + l * 147456, WgPk + l * 442368,
                                            qpreB + l * 1280, gatw + l * 768, gatb + l,
                                            adj, smask, cbh + l * 1152, pbi + l * 1152,
                                            MgB, kpB + l * 40960,
                                            ctrB_ + l * 1280, ctrB_ + 2560 + l * 1280);
    }

    // Back-end MLP + log_softmax
    gemm(Hcat, LDH, w0, LDH, b0, S2, 384, 1664, 384, 1, 0);
    gemm(S2, 384, w1, 384, b1, S1, 384, 384, 384, 1, 0);
    mlp_final<<<320, 256, 0, stream>>>(S1, w2, b2, out);
}

// Round 5
// 1701.202 us; speedup vs baseline: 5.2252x; 1.2595x over previous
//
#include <hip/hip_runtime.h>
#include <hip/hip_bf16.h>
#include <math.h>

// Problem constants
#define BB 16
#define NN 80
#define DH_ 384
#define LDH 1664   // Hcat row stride: [H0 | H1 | H2 | fused]

typedef unsigned int uint;

// ---------------------------------------------------------------------------
// 64x64 tiled f32 GEMM, 256 threads, 4x4/thread. Optional second weight
// tensor Wb for output rows >= 512 (fused U|V GEMMs). act: 0 none, 1 relu,
// 2 sigmoid, 3 sigmoid for o<512 else none.
// ---------------------------------------------------------------------------
__global__ __launch_bounds__(256)
void gemm64(const float* __restrict__ A, int lda,
            const float* __restrict__ W, const float* __restrict__ Wb, int ldw,
            const float* __restrict__ bias,
            float* __restrict__ C, int ldc,
            int K, int act, int accum)
{
    __shared__ float As[16][68];
    __shared__ float Bs[16][68];
    const int tid = threadIdx.x;
    const int tx = tid & 15, ty = tid >> 4;
    const int r0 = blockIdx.y * 64, o0 = blockIdx.x * 64;

    float acc[4][4];
#pragma unroll
    for (int u = 0; u < 4; ++u)
#pragma unroll
        for (int v = 0; v < 4; ++v) acc[u][v] = 0.f;

    const int srow = tid >> 2;            // 0..63
    const int kq = (tid & 3) << 2;        // 0,4,8,12
    const float* asrc = A + (r0 + srow) * lda;
    const float* wsrc;
    {
        int orow = o0 + srow;
        wsrc = (Wb && orow >= 512) ? (Wb + (orow - 512) * ldw) : (W + orow * ldw);
    }

    for (int kb = 0; kb < K; kb += 16) {
        float4 va = *(const float4*)(asrc + kb + kq);
        float4 vb = *(const float4*)(wsrc + kb + kq);
        As[kq + 0][srow] = va.x; As[kq + 1][srow] = va.y;
        As[kq + 2][srow] = va.z; As[kq + 3][srow] = va.w;
        Bs[kq + 0][srow] = vb.x; Bs[kq + 1][srow] = vb.y;
        Bs[kq + 2][srow] = vb.z; Bs[kq + 3][srow] = vb.w;
        __syncthreads();
#pragma unroll
        for (int k = 0; k < 16; ++k) {
            float4 a = *(const float4*)&As[k][ty * 4];
            float4 bv = *(const float4*)&Bs[k][tx * 4];
            float av[4] = {a.x, a.y, a.z, a.w};
            float bb[4] = {bv.x, bv.y, bv.z, bv.w};
#pragma unroll
            for (int u = 0; u < 4; ++u)
#pragma unroll
                for (int v = 0; v < 4; ++v)
                    acc[u][v] = fmaf(av[u], bb[v], acc[u][v]);
        }
        __syncthreads();
    }
#pragma unroll
    for (int u = 0; u < 4; ++u) {
        int r = r0 + ty * 4 + u;
#pragma unroll
        for (int v = 0; v < 4; ++v) {
            int o = o0 + tx * 4 + v;
            float c = acc[u][v];
            if (bias) c += bias[o];
            if (accum) c += C[r * ldc + o];
            if (act == 1) c = fmaxf(c, 0.f);
            else if (act == 2) c = 1.f / (1.f + expf(-c));
            else if (act == 3 && o < 512) c = 1.f / (1.f + expf(-c));
            C[r * ldc + o] = c;
        }
    }
}

// c_ = T1[:, :512]*T2[:, :512] -> CBuf ; Hcat fused col += V1+V2 partial sums
__global__ void ew2(const float* __restrict__ T1, const float* __restrict__ T2,
                    float* __restrict__ CBuf, float* __restrict__ Hc)
{
    int idx = blockIdx.x * 256 + threadIdx.x;  // < 655360
    int r = idx >> 9, c = idx & 511;
    CBuf[idx] = T1[r * 1024 + c] * T2[r * 1024 + c];
    Hc[r * LDH + 1152 + c] = T1[r * 1024 + 512 + c] + T2[r * 1024 + 512 + c];
}

// ---- bf16 pack helpers (RNE) ----
__device__ __forceinline__ uint packbf(float lo, float hi)
{
    uint a = __float_as_uint(lo);
    a = (a + 0x7fffu + ((a >> 16) & 1u)) >> 16;
    uint b = __float_as_uint(hi);
    b = (b + 0x7fffu + ((b >> 16) & 1u)) & 0xffff0000u;
    return a | b;
}
__device__ __forceinline__ float bflo(uint u) { return __uint_as_float(u << 16); }
__device__ __forceinline__ float bfhi(uint u) { return __uint_as_float(u & 0xffff0000u); }

// WgPk[l][g][k=384][cp=72]: packed bf16 pair for gate cols c=2cp, 2cp+1
__global__ void trans_wg3(const float* __restrict__ cwh, const float* __restrict__ pwi,
                          uint* __restrict__ WgPk)
{
    int idx = blockIdx.x * 256 + threadIdx.x;  // < 884736
    int l = idx / 442368;
    int r = idx % 442368;
    int g = r / 27648;
    int r2 = r % 27648;
    int k = r2 / 72, cp = r2 % 72;
    float v[2];
#pragma unroll
    for (int u = 0; u < 2; ++u) {
        int c = 2 * cp + u;
        int idx6 = c / 24, o = c % 24, d = g * 24 + o;
        v[u] = (idx6 < 3) ? cwh[l * 442368 + (idx6 * 384 + d) * 384 + k]
                          : pwi[l * 442368 + ((idx6 - 3) * 384 + d) * 384 + k];
    }
    WgPk[idx] = packbf(v[0], v[1]);
}

// WrPk[l][g][k=384][dl=24]: packed bf16 (Wr0[g*24+dl][k], Wr1[g*24+dl][k])
__global__ void trans_wr3(const float* __restrict__ Wr0, const float* __restrict__ Wr1,
                          uint* __restrict__ WrPk)
{
    int idx = blockIdx.x * 256 + threadIdx.x;  // < 294912
    int l = idx / 147456;
    int r = idx % 147456;
    int g = r / 9216;
    int r2 = r % 9216;
    int k = r2 / 24, dl = r2 % 24;
    int row = g * 24 + dl;
    float w0 = Wr0[l * 147456 + row * 384 + k];
    float w1 = Wr1[l * 147456 + row * 384 + k];
    WrPk[idx] = packbf(w0, w1);
}

// Concatenated gPre weights/bias: gw[l][o<2304][k<384], gb[l][o]
__global__ void gpre_prep(const float* __restrict__ cwi, const float* __restrict__ pwh,
                          const float* __restrict__ cbi, const float* __restrict__ pbh,
                          float* __restrict__ gw, float* __restrict__ gb_)
{
    int idx = blockIdx.x * 256 + threadIdx.x;  // < 1769472
    int l = idx / 884736;
    int r = idx % 884736;
    int o = r / 384, k = r % 384;
    gw[idx] = (o < 1152) ? cwi[l * 442368 + o * 384 + k]
                         : pwh[l * 442368 + (o - 1152) * 384 + k];
    if (k == 0)
        gb_[l * 2304 + o] = (o < 1152) ? cbi[l * 1152 + o] : pbh[l * 1152 + o - 1152];
}

// q[row] = dot(Hc[row, hin:hin+384], wq)
__global__ __launch_bounds__(256)
void qpre_k(const float* __restrict__ Hc, int hin, const float* __restrict__ wq,
            float* __restrict__ q)
{
    int wave = threadIdx.x >> 6, lane = threadIdx.x & 63;
    int row = blockIdx.x * 4 + wave;   // < 1280
    const float* hp = Hc + row * LDH + hin;
    float s = 0.f;
#pragma unroll
    for (int u = 0; u < 6; ++u) s = fmaf(hp[lane + 64 * u], wq[lane + 64 * u], s);
#pragma unroll
    for (int m = 1; m < 64; m <<= 1) s += __shfl_xor(s, m);
    if (lane == 0) q[row] = s;
}

#define ALOADU(p)     __hip_atomic_load((p), __ATOMIC_RELAXED, __HIP_MEMORY_SCOPE_AGENT)
#define ASTOREU(p, v) __hip_atomic_store((p), (v), __ATOMIC_RELAXED, __HIP_MEMORY_SCOPE_AGENT)

// Poll the 16 seq dwords (offset 31 of each 32-dword line) until all == expect.
__device__ __forceinline__ void pollX(const uint* Xs, uint expect)
{
    if (threadIdx.x < 64) {
        for (;;) {
            uint s = expect;
            if (threadIdx.x < 16)
                s = ALOADU(Xs + threadIdx.x * 32 + 31);
            if (__ballot(s == expect) == ~0ull) break;
            __builtin_amdgcn_s_sleep(1);
        }
    }
    __syncthreads();
}

// ---------------------------------------------------------------------------
// Sliced scan v5: 256 WGs = 16 b x 16 slices, 512 threads, weights in LDS,
// seq-tagged 128B exchange lines (X1: M-slice, X2: h-slice + kv partial).
// ---------------------------------------------------------------------------
__global__ __launch_bounds__(512)
void scan5(float* Hc, int hin, int hout,
           const float* __restrict__ gPre,
           const uint* __restrict__ WrPkl,   // [16][384][24]
           const uint* __restrict__ WgPkl,   // [16][384][72]
           const float* __restrict__ qpre,
           const float* __restrict__ gatwl,
           const float* __restrict__ gatbl,
           const int* __restrict__ adj,
           const int* __restrict__ smask,
           const float* __restrict__ cbh,
           const float* __restrict__ pbi,
           uint* __restrict__ X1,            // [16 b][2 slot][16 g][32 dw]
           uint* __restrict__ X2)
{
    const int wg = blockIdx.x;
    const int b = wg >> 4, g = wg & 15;
    const int t = threadIdx.x;

    extern __shared__ uint WgL[];    // [384][72] packed, 110592 B
    __shared__ uint WrL[384 * 25];   // padded stride 25
    __shared__ uint Pc16[NN][25];    // packed (P0,P1), padded
    __shared__ float kvS[NN];
    __shared__ float2 ws01[NN];
    __shared__ float Mv[DH_];
    __shared__ float uA[864];        // hrow[384] / gpart[6][144]
    __shared__ float gs[144];
    __shared__ float karr[16];

    uint* X1b = X1 + b * (2 * 16 * 32);
    uint* X2b = X2 + b * (2 * 16 * 32);

    {   // preload packed weights into LDS
        const uint* src = WgPkl + g * 27648;
        for (int idx = t; idx < 27648; idx += 512) WgL[idx] = src[idx];
        const uint* src2 = WrPkl + g * 9216;
        for (int idx = t; idx < 9216; idx += 512) {
            int k = idx / 24, dl = idx % 24;
            WrL[k * 25 + dl] = src2[idx];
        }
    }
    __syncthreads();

    const float gb = gatbl[0];

    for (int i = 0; i < NN; ++i) {
        const int rowi = b * NN + i;

        if (i > 0) {
            // ---- poll + load h(i-1), kv partials from X2 lines
            uint* Xs2 = X2b + ((i - 1) & 1) * (16 * 32);
            pollX(Xs2, (uint)i);
            if (t < 384) uA[t] = __uint_as_float(ALOADU(Xs2 + (t / 24) * 32 + (t % 24)));
            else if (t < 400) karr[t - 384] = __uint_as_float(ALOADU(Xs2 + (t - 384) * 32 + 24));
            __syncthreads();

            // ---- kv[i-1] + P-update for row i-1 (LDS bf16 weights)
            if (t == 400) {
                float s = 0.f;
#pragma unroll
                for (int u = 0; u < 16; ++u) s += karr[u];
                kvS[i - 1] = s;
            }
            if (t < 384) {
                int dl0 = t >> 4, sub = t & 15, part = sub & 7, half = sub >> 3;
                float acc = 0.f;
#pragma unroll 8
                for (int m = 0; m < 48; ++m) {
                    int k = part + 8 * m;
                    uint u = WrL[k * 25 + dl0];
                    float w = half ? bfhi(u) : bflo(u);
                    acc = fmaf(w, uA[k], acc);
                }
                acc += __shfl_xor(acc, 1);
                acc += __shfl_xor(acc, 2);
                acc += __shfl_xor(acc, 4);
                float other = __shfl_xor(acc, 8);
                if (sub == 0) Pc16[i - 1][dl0] = packbf(acc, other);
            }
            __syncthreads();

            // ---- masked softmax (wave 0)
            if (t < 64) {
                float q = qpre[rowi] + gb;
                int j0 = t, j1 = t + 64;
                float a0v = -1e30f, a1v = -1e30f;
                if (j0 < i && adj[rowi * NN + j0] != 0) a0v = q + kvS[j0];
                if (j1 < i && adj[rowi * NN + j1] != 0) a1v = q + kvS[j1];
                float mx = fmaxf(a0v, a1v);
#pragma unroll
                for (int m = 1; m < 64; m <<= 1) mx = fmaxf(mx, __shfl_xor(mx, m));
                float e0 = expf(a0v - mx);
                float e1 = (j1 < NN) ? expf(a1v - mx) : 0.f;
                float ss = e0 + e1;
#pragma unroll
                for (int m = 1; m < 64; m <<= 1) ss += __shfl_xor(ss, m);
                float inv = 1.f / ss;
                float w0 = e0 * inv;
                float s0 = (float)smask[rowi * NN + j0];
                ws01[j0] = make_float2(w0 * s0, w0 - w0 * s0);
                if (j1 < NN) {
                    float w1 = e1 * inv;
                    float s1 = (float)smask[rowi * NN + j1];
                    ws01[j1] = make_float2(w1 * s1, w1 - w1 * s1);
                }
            }
            __syncthreads();

            // ---- M slice -> X1 line (data, drain, then seq)
            uint* Xs1 = X1b + (i & 1) * (16 * 32);
            if (t < 384) {
                int dl0 = t >> 4, sub = t & 15;
                float acc = 0.f;
                for (int j = sub; j < i; j += 16) {
                    uint u = Pc16[j][dl0];
                    float2 w = ws01[j];
                    acc = fmaf(w.x, bflo(u), acc);
                    acc = fmaf(w.y, bfhi(u), acc);
                }
                acc += __shfl_xor(acc, 1);
                acc += __shfl_xor(acc, 2);
                acc += __shfl_xor(acc, 4);
                acc += __shfl_xor(acc, 8);
                if (sub == 0) ASTOREU(Xs1 + g * 32 + dl0, __float_as_uint(acc));
            }
            asm volatile("s_waitcnt vmcnt(0)" ::: "memory");
            __syncthreads();
            if (t == 0) ASTOREU(Xs1 + g * 32 + 31, (uint)(i + 1));

            // ---- gather full M
            pollX(Xs1, (uint)(i + 1));
            if (t < 384) Mv[t] = __uint_as_float(ALOADU(Xs1 + (t / 24) * 32 + (t % 24)));
            __syncthreads();
        } else {
            if (t < 384) Mv[t] = 0.f;
            __syncthreads();
        }

        // ---- gate slice from LDS bf16: 144 outputs = 72 pairs x 6 k-chunks
        if (t < 432) {
            int cp = t % 72, kt = t / 72;
            int kbase = kt * 64;
            float a0 = 0.f, a1 = 0.f;
#pragma unroll 8
            for (int kk = 0; kk < 64; ++kk) {
                uint u = WgL[(kbase + kk) * 72 + cp];
                float m = Mv[kbase + kk];
                a0 = fmaf(bflo(u), m, a0);
                a1 = fmaf(bfhi(u), m, a1);
            }
            uA[kt * 144 + 2 * cp] = a0;
            uA[kt * 144 + 2 * cp + 1] = a1;
        }
        __syncthreads();
        if (t < 144) {
            float s = 0.f;
#pragma unroll
            for (int kt = 0; kt < 6; ++kt) s += uA[kt * 144 + t];
            gs[t] = s;
        }
        __syncthreads();

        // ---- GRU cells for 24 dims -> Hc + X2 line
        uint* Xs2w = X2b + (i & 1) * (16 * 32);
        if (t < 32) {
            float kp = 0.f;
            if (t < 24) {
                int dg = g * 24 + t;
                const float* gp = gPre + rowi * 2304;
                float m = Mv[dg];
                float gir = gp[dg], giz = gp[384 + dg], gin = gp[768 + dg];
                float ghr = gs[t] + cbh[dg];
                float ghz = gs[24 + t] + cbh[384 + dg];
                float ghn = gs[48 + t] + cbh[768 + dg];
                float r = 1.f / (1.f + expf(-(gir + ghr)));
                float z = 1.f / (1.f + expf(-(giz + ghz)));
                float n = tanhf(gin + r * ghn);
                float Cc = (1.f - z) * n + z * m;
                float pir = gs[72 + t] + pbi[dg];
                float piz = gs[96 + t] + pbi[384 + dg];
                float pin = gs[120 + t] + pbi[768 + dg];
                float phr = gp[1152 + dg], phz = gp[1536 + dg], phn = gp[1920 + dg];
                float r2 = 1.f / (1.f + expf(-(pir + phr)));
                float z2 = 1.f / (1.f + expf(-(piz + phz)));
                float n2 = tanhf(pin + r2 * phn);
                float x = Hc[rowi * LDH + hin + dg];
                float Pp = (1.f - z2) * n2 + z2 * x;
                float h = Cc + Pp;
                Hc[rowi * LDH + hout + dg] = h;
                ASTOREU(Xs2w + g * 32 + t, __float_as_uint(h));
                kp = h * gatwl[384 + dg];
            }
#pragma unroll
            for (int m = 16; m >= 1; m >>= 1) kp += __shfl_down(kp, m);
            if (t == 0) ASTOREU(Xs2w + g * 32 + 24, __float_as_uint(kp));
        }
        asm volatile("s_waitcnt vmcnt(0)" ::: "memory");
        __syncthreads();
        if (t == 0) ASTOREU(Xs2w + g * 32 + 31, (uint)(i + 1));
        // next iteration's pollX provides the step barrier
    }
}

// logits (7) + log_softmax, one wave per row
__global__ __launch_bounds__(256)
void mlp_final(const float* __restrict__ h, const float* __restrict__ w2,
               const float* __restrict__ b2, float* __restrict__ out)
{
    int wave = threadIdx.x >> 6, lane = threadIdx.x & 63;
    int r = blockIdx.x * 4 + wave;   // < 1280
    float hreg[6];
#pragma unroll
    for (int m = 0; m < 6; ++m) hreg[m] = h[r * 384 + lane + 64 * m];
    float logit[7];
#pragma unroll
    for (int c = 0; c < 7; ++c) {
        float s = 0.f;
#pragma unroll
        for (int m = 0; m < 6; ++m)
            s = fmaf(hreg[m], w2[c * 384 + lane + 64 * m], s);
#pragma unroll
        for (int m = 1; m < 64; m <<= 1) s += __shfl_xor(s, m);
        logit[c] = s + b2[c];
    }
    float mx = logit[0];
#pragma unroll
    for (int c = 1; c < 7; ++c) mx = fmaxf(mx, logit[c]);
    float se = 0.f;
#pragma unroll
    for (int c = 0; c < 7; ++c) se += expf(logit[c] - mx);
    float lse = mx + logf(se);
    if (lane < 7) out[r * 7 + lane] = logit[lane] - lse;
}

extern "C" void kernel_launch(void* const* d_in, const int* in_sizes, int n_in,
                              void* d_out, int out_size, void* d_ws, size_t ws_size,
                              hipStream_t stream)
{
    const float* ftext = (const float*)d_in[0];
    const float* faud  = (const float*)d_in[1];
    const int*   adj   = (const int*)d_in[2];
    const int*   smask = (const int*)d_in[3];
    const float* U1    = (const float*)d_in[6];
    const float* U2    = (const float*)d_in[7];
    const float* Pw    = (const float*)d_in[8];
    const float* Pb    = (const float*)d_in[9];
    const float* V1    = (const float*)d_in[10];
    const float* V2    = (const float*)d_in[11];
    const float* fc1w  = (const float*)d_in[12];
    const float* fc1b  = (const float*)d_in[13];
    const float* gatw  = (const float*)d_in[14];
    const float* gatb  = (const float*)d_in[15];
    const float* Wr0   = (const float*)d_in[16];
    const float* Wr1   = (const float*)d_in[17];
    const float* cwi   = (const float*)d_in[18];
    const float* cwh   = (const float*)d_in[19];
    const float* cbi   = (const float*)d_in[20];
    const float* cbh   = (const float*)d_in[21];
    const float* pwi   = (const float*)d_in[22];
    const float* pwh   = (const float*)d_in[23];
    const float* pbi   = (const float*)d_in[24];
    const float* pbh   = (const float*)d_in[25];
    const float* w0    = (const float*)d_in[26];
    const float* b0    = (const float*)d_in[27];
    const float* w1    = (const float*)d_in[28];
    const float* b1    = (const float*)d_in[29];
    const float* w2    = (const float*)d_in[30];
    const float* b2    = (const float*)d_in[31];
    float* out = (float*)d_out;
    float* ws = (float*)d_ws;

    // workspace layout (f32 words)
    float* Hcat  = ws;                        // 2,129,920
    float* gPre  = Hcat + 2129920;            // 2,949,120 (front-end reuses as T1|T2; back-end as h2)
    float* T1b   = gPre;                      // 1,310,720
    float* T2b   = gPre + 1310720;            // 1,310,720
    float* CBuf  = gPre + 2949120;            // 655,360 (later h1)
    uint*  WgPk  = (uint*)(CBuf + 655360);    // 884,736
    uint*  WrPk  = WgPk + 884736;             // 294,912
    float* gw    = (float*)(WrPk + 294912);   // 1,769,472
    float* gb_   = gw + 1769472;              // 4,608
    float* qpreB = gb_ + 4608;                // 2,560
    uint*  Xbase = (uint*)(qpreB + 2560);     // 65,536 uints (4 x 16KB regions)
    uint*  X1l0  = Xbase;
    uint*  X2l0  = Xbase + 16384;
    uint*  X1l1  = Xbase + 32768;
    uint*  X2l1  = Xbase + 49152;

    dim3 blk(256);
    auto gemm = [&](const float* A, int lda, const float* W, const float* Wb, int ldw,
                    const float* bias, float* C, int ldc, int K, int O,
                    int act, int accum) {
        dim3 grid(O / 64, 1280 / 64);
        gemm64<<<grid, blk, 0, stream>>>(A, lda, W, Wb, ldw, bias, C, ldc, K, act, accum);
    };

    // zero exchange-line tags (replay safety)
    hipMemsetAsync(Xbase, 0, 65536 * sizeof(uint), stream);

    // weight prep (independent of front-end)
    trans_wg3<<<3456, 256, 0, stream>>>(cwh, pwi, WgPk);
    trans_wr3<<<1152, 256, 0, stream>>>(Wr0, Wr1, WrPk);
    gpre_prep<<<6912, 256, 0, stream>>>(cwi, pwh, cbi, pbh, gw, gb_);

    // Front-end fusion: T1 = [sig(text@U1^T) | text@V1^T], T2 = [sig(aud@U2^T) | aud@V2^T]
    gemm(ftext, 1024, U1, V1, 1024, nullptr, T1b, 1024, 1024, 1024, 3, 0);
    gemm(faud,  512,  U2, V2, 512,  nullptr, T2b, 1024, 512,  1024, 3, 0);
    ew2<<<2560, 256, 0, stream>>>(T1b, T2b, CBuf, Hcat);
    gemm(CBuf, 512, Pw, nullptr, 512, Pb, Hcat + 1152, LDH, 512, 512, 0, 1);   // fused
    gemm(Hcat + 1152, LDH, fc1w, nullptr, 512, fc1b, Hcat, LDH, 512, 384, 1, 0); // H0

    // Two GAT/GRU layers
    for (int l = 0; l < 2; ++l) {
        gemm(Hcat + l * 384, LDH, gw + l * 884736, nullptr, 384, gb_ + l * 2304,
             gPre, 2304, 384, 2304, 0, 0);
        qpre_k<<<320, 256, 0, stream>>>(Hcat, l * 384, gatw + l * 768, qpreB + l * 1280);
        scan5<<<256, 512, 110592, stream>>>(Hcat, l * 384, (l + 1) * 384, gPre,
                                            WrPk + l * 147456, WgPk + l * 442368,
                                            qpreB + l * 1280, gatw + l * 768, gatb + l,
                                            adj, smask, cbh + l * 1152, pbi + l * 1152,
                                            l ? X1l1 : X1l0, l ? X2l1 : X2l0);
    }

    // Back-end MLP + log_softmax
    gemm(Hcat, LDH, w0, nullptr, LDH, b0, CBuf, 384, 1664, 384, 1, 0);   // h1
    gemm(CBuf, 384, w1, nullptr, 384, b1, gPre, 384, 384, 384, 1, 0);    // h2
    mlp_final<<<320, 256, 0, stream>>>(gPre, w2, b2, out);
}

// Round 9
// 1636.424 us; speedup vs baseline: 5.4320x; 1.0396x over previous
//
#include <hip/hip_runtime.h>
#include <hip/hip_bf16.h>
#include <math.h>

// Problem constants
#define BB 16
#define NN 80
#define DH_ 384
#define LDH 1664   // Hcat row stride: [H0 | H1 | H2 | fused]

typedef unsigned int uint;
typedef unsigned long long u64;

// ---------------------------------------------------------------------------
// 64x64 tiled f32 GEMM, 256 threads, 4x4/thread. Optional second weight
// tensor Wb for output rows >= 512 (fused U|V GEMMs). act: 0 none, 1 relu,
// 2 sigmoid, 3 sigmoid for o<512 else none.
// ---------------------------------------------------------------------------
__global__ __launch_bounds__(256)
void gemm64(const float* __restrict__ A, int lda,
            const float* __restrict__ W, const float* __restrict__ Wb, int ldw,
            const float* __restrict__ bias,
            float* __restrict__ C, int ldc,
            int K, int act, int accum)
{
    __shared__ float As[16][68];
    __shared__ float Bs[16][68];
    const int tid = threadIdx.x;
    const int tx = tid & 15, ty = tid >> 4;
    const int r0 = blockIdx.y * 64, o0 = blockIdx.x * 64;

    float acc[4][4];
#pragma unroll
    for (int u = 0; u < 4; ++u)
#pragma unroll
        for (int v = 0; v < 4; ++v) acc[u][v] = 0.f;

    const int srow = tid >> 2;            // 0..63
    const int kq = (tid & 3) << 2;        // 0,4,8,12
    const float* asrc = A + (r0 + srow) * lda;
    const float* wsrc;
    {
        int orow = o0 + srow;
        wsrc = (Wb && orow >= 512) ? (Wb + (orow - 512) * ldw) : (W + orow * ldw);
    }

    for (int kb = 0; kb < K; kb += 16) {
        float4 va = *(const float4*)(asrc + kb + kq);
        float4 vb = *(const float4*)(wsrc + kb + kq);
        As[kq + 0][srow] = va.x; As[kq + 1][srow] = va.y;
        As[kq + 2][srow] = va.z; As[kq + 3][srow] = va.w;
        Bs[kq + 0][srow] = vb.x; Bs[kq + 1][srow] = vb.y;
        Bs[kq + 2][srow] = vb.z; Bs[kq + 3][srow] = vb.w;
        __syncthreads();
#pragma unroll
        for (int k = 0; k < 16; ++k) {
            float4 a = *(const float4*)&As[k][ty * 4];
            float4 bv = *(const float4*)&Bs[k][tx * 4];
            float av[4] = {a.x, a.y, a.z, a.w};
            float bb[4] = {bv.x, bv.y, bv.z, bv.w};
#pragma unroll
            for (int u = 0; u < 4; ++u)
#pragma unroll
                for (int v = 0; v < 4; ++v)
                    acc[u][v] = fmaf(av[u], bb[v], acc[u][v]);
        }
        __syncthreads();
    }
#pragma unroll
    for (int u = 0; u < 4; ++u) {
        int r = r0 + ty * 4 + u;
#pragma unroll
        for (int v = 0; v < 4; ++v) {
            int o = o0 + tx * 4 + v;
            float c = acc[u][v];
            if (bias) c += bias[o];
            if (accum) c += C[r * ldc + o];
            if (act == 1) c = fmaxf(c, 0.f);
            else if (act == 2) c = 1.f / (1.f + expf(-c));
            else if (act == 3 && o < 512) c = 1.f / (1.f + expf(-c));
            C[r * ldc + o] = c;
        }
    }
}

// c_ = T1[:, :512]*T2[:, :512] -> CBuf ; Hcat fused col = V1+V2 partial sums
__global__ void ew2(const float* __restrict__ T1, const float* __restrict__ T2,
                    float* __restrict__ CBuf, float* __restrict__ Hc)
{
    int idx = blockIdx.x * 256 + threadIdx.x;  // < 655360
    int r = idx >> 9, c = idx & 511;
    CBuf[idx] = T1[r * 1024 + c] * T2[r * 1024 + c];
    Hc[r * LDH + 1152 + c] = T1[r * 1024 + 512 + c] + T2[r * 1024 + 512 + c];
}

// ---- bf16 pack helpers (RNE) ----
__device__ __forceinline__ uint packbf(float lo, float hi)
{
    uint a = __float_as_uint(lo);
    a = (a + 0x7fffu + ((a >> 16) & 1u)) >> 16;
    uint b = __float_as_uint(hi);
    b = (b + 0x7fffu + ((b >> 16) & 1u)) & 0xffff0000u;
    return a | b;
}
__device__ __forceinline__ float bflo(uint u) { return __uint_as_float(u << 16); }
__device__ __forceinline__ float bfhi(uint u) { return __uint_as_float(u & 0xffff0000u); }

// WgPk[l][g][k=384][cp=72]: packed bf16 pair for gate cols c=2cp, 2cp+1
__global__ void trans_wg3(const float* __restrict__ cwh, const float* __restrict__ pwi,
                          uint* __restrict__ WgPk)
{
    int idx = blockIdx.x * 256 + threadIdx.x;  // < 884736
    int l = idx / 442368;
    int r = idx % 442368;
    int g = r / 27648;
    int r2 = r % 27648;
    int k = r2 / 72, cp = r2 % 72;
    float v[2];
#pragma unroll
    for (int u = 0; u < 2; ++u) {
        int c = 2 * cp + u;
        int idx6 = c / 24, o = c % 24, d = g * 24 + o;
        v[u] = (idx6 < 3) ? cwh[l * 442368 + (idx6 * 384 + d) * 384 + k]
                          : pwi[l * 442368 + ((idx6 - 3) * 384 + d) * 384 + k];
    }
    WgPk[idx] = packbf(v[0], v[1]);
}

// WrPk[l][g][k=384][dl=24]: packed bf16 (Wr0[g*24+dl][k], Wr1[g*24+dl][k])
__global__ void trans_wr3(const float* __restrict__ Wr0, const float* __restrict__ Wr1,
                          uint* __restrict__ WrPk)
{
    int idx = blockIdx.x * 256 + threadIdx.x;  // < 294912
    int l = idx / 147456;
    int r = idx % 147456;
    int g = r / 9216;
    int r2 = r % 9216;
    int k = r2 / 24, dl = r2 % 24;
    int row = g * 24 + dl;
    float w0 = Wr0[l * 147456 + row * 384 + k];
    float w1 = Wr1[l * 147456 + row * 384 + k];
    WrPk[idx] = packbf(w0, w1);
}

// Concatenated gPre weights/bias: gw[l][o<2304][k<384], gb[l][o]
__global__ void gpre_prep(const float* __restrict__ cwi, const float* __restrict__ pwh,
                          const float* __restrict__ cbi, const float* __restrict__ pbh,
                          float* __restrict__ gw, float* __restrict__ gb_)
{
    int idx = blockIdx.x * 256 + threadIdx.x;  // < 1769472
    int l = idx / 884736;
    int r = idx % 884736;
    int o = r / 384, k = r % 384;
    gw[idx] = (o < 1152) ? cwi[l * 442368 + o * 384 + k]
                         : pwh[l * 442368 + (o - 1152) * 384 + k];
    if (k == 0)
        gb_[l * 2304 + o] = (o < 1152) ? cbi[l * 1152 + o] : pbh[l * 1152 + o - 1152];
}

// q[row] = dot(Hc[row, hin:hin+384], wq)
__global__ __launch_bounds__(256)
void qpre_k(const float* __restrict__ Hc, int hin, const float* __restrict__ wq,
            float* __restrict__ q)
{
    int wave = threadIdx.x >> 6, lane = threadIdx.x & 63;
    int row = blockIdx.x * 4 + wave;   // < 1280
    const float* hp = Hc + row * LDH + hin;
    float s = 0.f;
#pragma unroll
    for (int u = 0; u < 6; ++u) s = fmaf(hp[lane + 64 * u], wq[lane + 64 * u], s);
#pragma unroll
    for (int m = 1; m < 64; m <<= 1) s += __shfl_xor(s, m);
    if (lane == 0) q[row] = s;
}

// ---- exchange primitives: 8B aligned relaxed agent-scope atomics ONLY ----
// payload in lo 32 bits, sequence tag in hi 32 bits: arrival is detection.
#define ALD64(p)    __hip_atomic_load((p), __ATOMIC_RELAXED, __HIP_MEMORY_SCOPE_AGENT)
#define AST64(p, v) __hip_atomic_store((p), (v), __ATOMIC_RELAXED, __HIP_MEMORY_SCOPE_AGENT)

// ---------------------------------------------------------------------------
// Sliced scan v9: 256 WGs = 16 b x 16 slices, 512 threads, weights in LDS.
// v5-proven protocol, latency-optimized: every cross-WG word is a 64-bit
// (seq | payload) atomic; consumers poll the data words directly via
// __syncthreads_count, so one one-way propagation replaces the old
// store+drain+tag+poll+load chain. No fences, no hwreg, no sc0, no
// cross-batch sync. X buffers zeroed by stream-ordered memset per launch.
// ---------------------------------------------------------------------------
__global__ __launch_bounds__(512)
void scan9(float* Hc, int hin, int hout,
           const float* __restrict__ gPre,
           const uint* __restrict__ WrPkl,   // [16][384][24]
           const uint* __restrict__ WgPkl,   // [16][384][72]
           const float* __restrict__ qpre,
           const float* __restrict__ gatwl,
           const float* __restrict__ gatbl,
           const int* __restrict__ adj,
           const int* __restrict__ smask,
           const float* __restrict__ cbh,
           const float* __restrict__ pbi,
           u64* __restrict__ X1,             // [16 b][2 slot][384]  (M words)
           u64* __restrict__ X2)             // [16 b][2 slot][400]  (h | kv)
{
    const int wg = blockIdx.x;
    const int b = wg >> 4, g = wg & 15;
    const int t = threadIdx.x;

    extern __shared__ uint WgL[];    // [384][72] packed, 110592 B
    __shared__ uint WrL[384 * 25];   // padded stride 25
    __shared__ uint Pc16[NN][25];    // packed (P0,P1), padded
    __shared__ float kvS[NN];
    __shared__ float2 ws01[NN];
    __shared__ float Mv[DH_];
    __shared__ float uA[864];        // hrow[384] / gate partials / gp+x handoff
    __shared__ float gs[144];
    __shared__ float karr[16];

    {   // preload packed weights into LDS
        const uint* src = WgPkl + g * 27648;
        for (int idx = t; idx < 27648; idx += 512) WgL[idx] = src[idx];
        const uint* src2 = WrPkl + g * 9216;
        for (int idx = t; idx < 9216; idx += 512) {
            int k = idx / 24, dl = idx % 24;
            WrL[k * 25 + dl] = src2[idx];
        }
    }
    __syncthreads();

    u64* X1b = X1 + b * (2 * 384);
    u64* X2b = X2 + b * (2 * 400);
    const float gb = gatbl[0];

    // softmax-input prefetch registers (wave 0): current + next step
    int ca0 = 0, cs0 = 0, ca1 = 0, cs1 = 0;
    float cq = 0.f;
    int na0 = 0, ns0 = 0, na1 = 0, ns1 = 0;
    float nq = 0.f;

    // GRU-input prefetch registers
    float gpv = 0.f, xv = 0.f;

    for (int i = 0; i < NN; ++i) {
        const int rowi = b * NN + i;

        // ---- A. issue prefetches (registers; consumed later this step)
        if (t < 144) gpv = gPre[rowi * 2304 + (t / 24) * 384 + g * 24 + (t % 24)];
        else if (t < 168) xv = Hc[rowi * LDH + hin + g * 24 + (t - 144)];
        if (t < 64) {   // softmax inputs for step i+1
            int ip = (i + 1 < NN) ? (i + 1) : (NN - 1);
            int rp = b * NN + ip;
            na0 = adj[rp * NN + t];
            ns0 = smask[rp * NN + t];
            if (t + 64 < NN) { na1 = adj[rp * NN + t + 64]; ns1 = smask[rp * NN + t + 64]; }
            nq = qpre[rp];
        }

        if (i > 0) {
            // ---- B. poll X2 slot[(i-1)&1]: h(i-1) + kv partials, seq == i
            const u64* Xs2 = X2b + ((i - 1) & 1) * 400;
            u64 w = 0;
            for (;;) {
                int valid = 1;
                if (t < 400) {
                    w = ALD64(&Xs2[t]);
                    valid = ((uint)(w >> 32) == (uint)i);
                }
                if (__syncthreads_count(valid) == 512) break;
            }
            if (t < 384) uA[t] = __uint_as_float((uint)w);
            else if (t < 400) karr[t - 384] = __uint_as_float((uint)w);
            __syncthreads();

            // ---- C. kv[i-1] + P-update for row i-1 (LDS bf16 weights)
            if (t == 400) {
                float s = 0.f;
#pragma unroll
                for (int u = 0; u < 16; ++u) s += karr[u];
                kvS[i - 1] = s;
            }
            if (t < 384) {
                int dl0 = t >> 4, sub = t & 15, part = sub & 7, half = sub >> 3;
                float acc = 0.f;
#pragma unroll 8
                for (int m = 0; m < 48; ++m) {
                    int k = part + 8 * m;
                    uint u = WrL[k * 25 + dl0];
                    float w2_ = half ? bfhi(u) : bflo(u);
                    acc = fmaf(w2_, uA[k], acc);
                }
                acc += __shfl_xor(acc, 1);
                acc += __shfl_xor(acc, 2);
                acc += __shfl_xor(acc, 4);
                float other = __shfl_xor(acc, 8);
                if (sub == 0) Pc16[i - 1][dl0] = packbf(acc, other);
            }
            __syncthreads();

            // ---- D. masked softmax (wave 0) using prefetched inputs
            if (t < 64) {
                float q = cq + gb;
                int j0 = t, j1 = t + 64;
                float a0v = -1e30f, a1v = -1e30f;
                if (j0 < i && ca0 != 0) a0v = q + kvS[j0];
                if (j1 < i && ca1 != 0) a1v = q + kvS[j1];
                float mx = fmaxf(a0v, a1v);
#pragma unroll
                for (int m = 1; m < 64; m <<= 1) mx = fmaxf(mx, __shfl_xor(mx, m));
                float e0 = expf(a0v - mx);
                float e1 = (j1 < NN) ? expf(a1v - mx) : 0.f;
                float ss = e0 + e1;
#pragma unroll
                for (int m = 1; m < 64; m <<= 1) ss += __shfl_xor(ss, m);
                float inv = 1.f / ss;
                float w0 = e0 * inv;
                float s0 = (float)cs0;
                ws01[j0] = make_float2(w0 * s0, w0 - w0 * s0);
                if (j1 < NN) {
                    float w1 = e1 * inv;
                    float s1 = (float)cs1;
                    ws01[j1] = make_float2(w1 * s1, w1 - w1 * s1);
                }
            }
            __syncthreads();

            // ---- E. M slice -> X1 words (seq i+1 embedded; fire-and-forget)
            u64* Xs1 = X1b + (i & 1) * 384;
            if (t < 384) {
                int dl0 = t >> 4, sub = t & 15;
                float acc = 0.f;
                for (int j = sub; j < i; j += 16) {
                    uint u = Pc16[j][dl0];
                    float2 w2_ = ws01[j];
                    acc = fmaf(w2_.x, bflo(u), acc);
                    acc = fmaf(w2_.y, bfhi(u), acc);
                }
                acc += __shfl_xor(acc, 1);
                acc += __shfl_xor(acc, 2);
                acc += __shfl_xor(acc, 4);
                acc += __shfl_xor(acc, 8);
                if (sub == 0)
                    AST64(&Xs1[g * 24 + dl0],
                          ((u64)(uint)(i + 1) << 32) | (u64)__float_as_uint(acc));
            }

            // ---- F. poll X1 for full M (data embedded), seq == i+1
            {
                u64 wm = 0;
                for (;;) {
                    int valid = 1;
                    if (t < 384) {
                        wm = ALD64(&Xs1[t]);
                        valid = ((uint)(wm >> 32) == (uint)(i + 1));
                    }
                    if (__syncthreads_count(valid) == 512) break;
                }
                if (t < 384) Mv[t] = __uint_as_float((uint)wm);
            }
            __syncthreads();
        } else {
            if (t < 384) Mv[t] = 0.f;
            __syncthreads();
        }

        // rotate softmax prefetch registers (used at step i+1)
        if (t < 64) { ca0 = na0; cs0 = ns0; ca1 = na1; cs1 = ns1; cq = nq; }

        // ---- G. gate slice from LDS bf16: 144 outputs = 72 pairs x 6 k-chunks
        if (t < 432) {
            int cp = t % 72, kt = t / 72;
            int kbase = kt * 64;
            float a0 = 0.f, a1 = 0.f;
#pragma unroll 8
            for (int kk = 0; kk < 64; ++kk) {
                uint u = WgL[(kbase + kk) * 72 + cp];
                float m = Mv[kbase + kk];
                a0 = fmaf(bflo(u), m, a0);
                a1 = fmaf(bfhi(u), m, a1);
            }
            uA[kt * 144 + 2 * cp] = a0;
            uA[kt * 144 + 2 * cp + 1] = a1;
        }
        __syncthreads();
        if (t < 144) {
            float s = 0.f;
#pragma unroll
            for (int kt = 0; kt < 6; ++kt) s += uA[kt * 144 + t];
            gs[t] = s;
        }
        __syncthreads();

        // ---- H. hand off prefetched gp/x registers into (now free) uA
        if (t < 144) uA[t] = gpv;
        else if (t < 168) uA[t] = xv;
        __syncthreads();

        // ---- I. GRU cells for 24 dims -> Hc + X2 words (seq i+1 embedded)
        u64* Xs2w = X2b + (i & 1) * 400;
        if (t < 32) {
            float kp = 0.f;
            if (t < 24) {
                int dg = g * 24 + t;
                float m = Mv[dg];
                float gir = uA[t], giz = uA[24 + t], gin = uA[48 + t];
                float ghr = gs[t] + cbh[dg];
                float ghz = gs[24 + t] + cbh[384 + dg];
                float ghn = gs[48 + t] + cbh[768 + dg];
                float r = 1.f / (1.f + expf(-(gir + ghr)));
                float z = 1.f / (1.f + expf(-(giz + ghz)));
                float n = tanhf(gin + r * ghn);
                float Cc = (1.f - z) * n + z * m;
                float pir = gs[72 + t] + pbi[dg];
                float piz = gs[96 + t] + pbi[384 + dg];
                float pin = gs[120 + t] + pbi[768 + dg];
                float phr = uA[72 + t], phz = uA[96 + t], phn = uA[120 + t];
                float r2 = 1.f / (1.f + expf(-(pir + phr)));
                float z2 = 1.f / (1.f + expf(-(piz + phz)));
                float n2 = tanhf(pin + r2 * phn);
                float x = uA[144 + t];
                float Pp = (1.f - z2) * n2 + z2 * x;
                float h = Cc + Pp;
                Hc[rowi * LDH + hout + dg] = h;
                AST64(&Xs2w[g * 24 + t],
                      ((u64)(uint)(i + 1) << 32) | (u64)__float_as_uint(h));
                kp = h * gatwl[384 + dg];
            }
#pragma unroll
            for (int m = 16; m >= 1; m >>= 1) kp += __shfl_down(kp, m);
            if (t == 0)
                AST64(&Xs2w[384 + g],
                      ((u64)(uint)(i + 1) << 32) | (u64)__float_as_uint(kp));
        }
        // no trailing barrier: next step's poll loop synchronizes the block,
        // and no LDS written in I is re-read before a barrier inside B.
    }
}

// logits (7) + log_softmax, one wave per row
__global__ __launch_bounds__(256)
void mlp_final(const float* __restrict__ h, const float* __restrict__ w2,
               const float* __restrict__ b2, float* __restrict__ out)
{
    int wave = threadIdx.x >> 6, lane = threadIdx.x & 63;
    int r = blockIdx.x * 4 + wave;   // < 1280
    float hreg[6];
#pragma unroll
    for (int m = 0; m < 6; ++m) hreg[m] = h[r * 384 + lane + 64 * m];
    float logit[7];
#pragma unroll
    for (int c = 0; c < 7; ++c) {
        float s = 0.f;
#pragma unroll
        for (int m = 0; m < 6; ++m)
            s = fmaf(hreg[m], w2[c * 384 + lane + 64 * m], s);
#pragma unroll
        for (int m = 1; m < 64; m <<= 1) s += __shfl_xor(s, m);
        logit[c] = s + b2[c];
    }
    float mx = logit[0];
#pragma unroll
    for (int c = 1; c < 7; ++c) mx = fmaxf(mx, logit[c]);
    float se = 0.f;
#pragma unroll
    for (int c = 0; c < 7; ++c) se += expf(logit[c] - mx);
    float lse = mx + logf(se);
    if (lane < 7) out[r * 7 + lane] = logit[lane] - lse;
}

extern "C" void kernel_launch(void* const* d_in, const int* in_sizes, int n_in,
                              void* d_out, int out_size, void* d_ws, size_t ws_size,
                              hipStream_t stream)
{
    const float* ftext = (const float*)d_in[0];
    const float* faud  = (const float*)d_in[1];
    const int*   adj   = (const int*)d_in[2];
    const int*   smask = (const int*)d_in[3];
    const float* U1    = (const float*)d_in[6];
    const float* U2    = (const float*)d_in[7];
    const float* Pw    = (const float*)d_in[8];
    const float* Pb    = (const float*)d_in[9];
    const float* V1    = (const float*)d_in[10];
    const float* V2    = (const float*)d_in[11];
    const float* fc1w  = (const float*)d_in[12];
    const float* fc1b  = (const float*)d_in[13];
    const float* gatw  = (const float*)d_in[14];
    const float* gatb  = (const float*)d_in[15];
    const float* Wr0   = (const float*)d_in[16];
    const float* Wr1   = (const float*)d_in[17];
    const float* cwi   = (const float*)d_in[18];
    const float* cwh   = (const float*)d_in[19];
    const float* cbi   = (const float*)d_in[20];
    const float* cbh   = (const float*)d_in[21];
    const float* pwi   = (const float*)d_in[22];
    const float* pwh   = (const float*)d_in[23];
    const float* pbi   = (const float*)d_in[24];
    const float* pbh   = (const float*)d_in[25];
    const float* w0    = (const float*)d_in[26];
    const float* b0    = (const float*)d_in[27];
    const float* w1    = (const float*)d_in[28];
    const float* b1    = (const float*)d_in[29];
    const float* w2    = (const float*)d_in[30];
    const float* b2    = (const float*)d_in[31];
    float* out = (float*)d_out;
    float* ws = (float*)d_ws;

    // workspace layout (f32 words)
    float* Hcat  = ws;                        // 2,129,920
    float* gPre  = Hcat + 2129920;            // 2,949,120 (front: T1|T2; back: h2)
    float* T1b   = gPre;                      // 1,310,720
    float* T2b   = gPre + 1310720;            // 1,310,720
    float* CBuf  = gPre + 2949120;            // 655,360 (later h1)
    uint*  WgPk  = (uint*)(CBuf + 655360);    // 884,736
    uint*  WrPk  = WgPk + 884736;             // 294,912
    float* gw    = (float*)(WrPk + 294912);   // 1,769,472
    float* gb_   = gw + 1769472;              // 4,608
    float* qpreB = gb_ + 4608;                // 2,560
    u64*   X1l0  = (u64*)(qpreB + 2560);      // 12,288 u64
    u64*   X2l0  = X1l0 + 12288;              // 12,800 u64
    u64*   X1l1  = X2l0 + 12800;              // 12,288 u64
    u64*   X2l1  = X1l1 + 12288;              // 12,800 u64

    dim3 blk(256);
    auto gemm = [&](const float* A, int lda, const float* W, const float* Wb, int ldw,
                    const float* bias, float* C, int ldc, int K, int O,
                    int act, int accum) {
        dim3 grid(O / 64, 1280 / 64);
        gemm64<<<grid, blk, 0, stream>>>(A, lda, W, Wb, ldw, bias, C, ldc, K, act, accum);
    };

    // zero ALL exchange words each launch (kills cross-launch seq aliasing)
    hipMemsetAsync(X1l0, 0, (size_t)(12288 + 12800) * 2 * sizeof(u64), stream);

    // weight prep (independent of front-end)
    trans_wg3<<<3456, 256, 0, stream>>>(cwh, pwi, WgPk);
    trans_wr3<<<1152, 256, 0, stream>>>(Wr0, Wr1, WrPk);
    gpre_prep<<<6912, 256, 0, stream>>>(cwi, pwh, cbi, pbh, gw, gb_);

    // Front-end fusion: T1 = [sig(text@U1^T) | text@V1^T], T2 = [sig(aud@U2^T) | aud@V2^T]
    gemm(ftext, 1024, U1, V1, 1024, nullptr, T1b, 1024, 1024, 1024, 3, 0);
    gemm(faud,  512,  U2, V2, 512,  nullptr, T2b, 1024, 512,  1024, 3, 0);
    ew2<<<2560, 256, 0, stream>>>(T1b, T2b, CBuf, Hcat);
    gemm(CBuf, 512, Pw, nullptr, 512, Pb, Hcat + 1152, LDH, 512, 512, 0, 1);     // fused
    gemm(Hcat + 1152, LDH, fc1w, nullptr, 512, fc1b, Hcat, LDH, 512, 384, 1, 0); // H0

    // Two GAT/GRU layers
    for (int l = 0; l < 2; ++l) {
        gemm(Hcat + l * 384, LDH, gw + l * 884736, nullptr, 384, gb_ + l * 2304,
             gPre, 2304, 384, 2304, 0, 0);
        qpre_k<<<320, 256, 0, stream>>>(Hcat, l * 384, gatw + l * 768, qpreB + l * 1280);
        scan9<<<256, 512, 110592, stream>>>(Hcat, l * 384, (l + 1) * 384, gPre,
                                            WrPk + l * 147456, WgPk + l * 442368,
                                            qpreB + l * 1280, gatw + l * 768, gatb + l,
                                            adj, smask, cbh + l * 1152, pbi + l * 1152,
                                            l ? X1l1 : X1l0, l ? X2l1 : X2l0);
    }

    // Back-end MLP + log_softmax
    gemm(Hcat, LDH, w0, nullptr, LDH, b0, CBuf, 384, 1664, 384, 1, 0);   // h1
    gemm(CBuf, 384, w1, nullptr, 384, b1, gPre, 384, 384, 384, 1, 0);    // h2
    mlp_final<<<320, 256, 0, stream>>>(gPre, w2, b2, out);
}

// Round 10
// 1384.737 us; speedup vs baseline: 6.4193x; 1.1818x over previous
//
#include <hip/hip_runtime.h>
#include <hip/hip_bf16.h>
#include <math.h>

// Problem constants
#define BB 16
#define NN 80
#define DH_ 384
#define LDH 1664   // Hcat row stride: [H0 | H1 | H2 | fused]

typedef unsigned int uint;
typedef unsigned long long u64;

// ---------------------------------------------------------------------------
// 64x64 tiled f32 GEMM, 256 threads, 4x4/thread. Optional second weight
// tensor Wb for output rows >= 512 (fused U|V GEMMs). act: 0 none, 1 relu,
// 2 sigmoid, 3 sigmoid for o<512 else none.
// ---------------------------------------------------------------------------
__global__ __launch_bounds__(256)
void gemm64(const float* __restrict__ A, int lda,
            const float* __restrict__ W, const float* __restrict__ Wb, int ldw,
            const float* __restrict__ bias,
            float* __restrict__ C, int ldc,
            int K, int act, int accum)
{
    __shared__ float As[16][68];
    __shared__ float Bs[16][68];
    const int tid = threadIdx.x;
    const int tx = tid & 15, ty = tid >> 4;
    const int r0 = blockIdx.y * 64, o0 = blockIdx.x * 64;

    float acc[4][4];
#pragma unroll
    for (int u = 0; u < 4; ++u)
#pragma unroll
        for (int v = 0; v < 4; ++v) acc[u][v] = 0.f;

    const int srow = tid >> 2;            // 0..63
    const int kq = (tid & 3) << 2;        // 0,4,8,12
    const float* asrc = A + (r0 + srow) * lda;
    const float* wsrc;
    {
        int orow = o0 + srow;
        wsrc = (Wb && orow >= 512) ? (Wb + (orow - 512) * ldw) : (W + orow * ldw);
    }

    for (int kb = 0; kb < K; kb += 16) {
        float4 va = *(const float4*)(asrc + kb + kq);
        float4 vb = *(const float4*)(wsrc + kb + kq);
        As[kq + 0][srow] = va.x; As[kq + 1][srow] = va.y;
        As[kq + 2][srow] = va.z; As[kq + 3][srow] = va.w;
        Bs[kq + 0][srow] = vb.x; Bs[kq + 1][srow] = vb.y;
        Bs[kq + 2][srow] = vb.z; Bs[kq + 3][srow] = vb.w;
        __syncthreads();
#pragma unroll
        for (int k = 0; k < 16; ++k) {
            float4 a = *(const float4*)&As[k][ty * 4];
            float4 bv = *(const float4*)&Bs[k][tx * 4];
            float av[4] = {a.x, a.y, a.z, a.w};
            float bb[4] = {bv.x, bv.y, bv.z, bv.w};
#pragma unroll
            for (int u = 0; u < 4; ++u)
#pragma unroll
                for (int v = 0; v < 4; ++v)
                    acc[u][v] = fmaf(av[u], bb[v], acc[u][v]);
        }
        __syncthreads();
    }
#pragma unroll
    for (int u = 0; u < 4; ++u) {
        int r = r0 + ty * 4 + u;
#pragma unroll
        for (int v = 0; v < 4; ++v) {
            int o = o0 + tx * 4 + v;
            float c = acc[u][v];
            if (bias) c += bias[o];
            if (accum) c += C[r * ldc + o];
            if (act == 1) c = fmaxf(c, 0.f);
            else if (act == 2) c = 1.f / (1.f + expf(-c));
            else if (act == 3 && o < 512) c = 1.f / (1.f + expf(-c));
            C[r * ldc + o] = c;
        }
    }
}

// c_ = T1[:, :512]*T2[:, :512] -> CBuf ; Hcat fused col = V1+V2 partial sums
__global__ void ew2(const float* __restrict__ T1, const float* __restrict__ T2,
                    float* __restrict__ CBuf, float* __restrict__ Hc)
{
    int idx = blockIdx.x * 256 + threadIdx.x;  // < 655360
    int r = idx >> 9, c = idx & 511;
    CBuf[idx] = T1[r * 1024 + c] * T2[r * 1024 + c];
    Hc[r * LDH + 1152 + c] = T1[r * 1024 + 512 + c] + T2[r * 1024 + 512 + c];
}

// ---- bf16 pack helpers (RNE) ----
__device__ __forceinline__ uint packbf(float lo, float hi)
{
    uint a = __float_as_uint(lo);
    a = (a + 0x7fffu + ((a >> 16) & 1u)) >> 16;
    uint b = __float_as_uint(hi);
    b = (b + 0x7fffu + ((b >> 16) & 1u)) & 0xffff0000u;
    return a | b;
}
__device__ __forceinline__ float bflo(uint u) { return __uint_as_float(u << 16); }
__device__ __forceinline__ float bfhi(uint u) { return __uint_as_float(u & 0xffff0000u); }

// WgPk[l][g][k=384][cp=72]: packed bf16 pair for gate cols c=2cp, 2cp+1
__global__ void trans_wg3(const float* __restrict__ cwh, const float* __restrict__ pwi,
                          uint* __restrict__ WgPk)
{
    int idx = blockIdx.x * 256 + threadIdx.x;  // < 884736
    int l = idx / 442368;
    int r = idx % 442368;
    int g = r / 27648;
    int r2 = r % 27648;
    int k = r2 / 72, cp = r2 % 72;
    float v[2];
#pragma unroll
    for (int u = 0; u < 2; ++u) {
        int c = 2 * cp + u;
        int idx6 = c / 24, o = c % 24, d = g * 24 + o;
        v[u] = (idx6 < 3) ? cwh[l * 442368 + (idx6 * 384 + d) * 384 + k]
                          : pwi[l * 442368 + ((idx6 - 3) * 384 + d) * 384 + k];
    }
    WgPk[idx] = packbf(v[0], v[1]);
}

// WrPk[l][g][k=384][dl=24]: packed bf16 (Wr0[g*24+dl][k], Wr1[g*24+dl][k])
__global__ void trans_wr3(const float* __restrict__ Wr0, const float* __restrict__ Wr1,
                          uint* __restrict__ WrPk)
{
    int idx = blockIdx.x * 256 + threadIdx.x;  // < 294912
    int l = idx / 147456;
    int r = idx % 147456;
    int g = r / 9216;
    int r2 = r % 9216;
    int k = r2 / 24, dl = r2 % 24;
    int row = g * 24 + dl;
    float w0 = Wr0[l * 147456 + row * 384 + k];
    float w1 = Wr1[l * 147456 + row * 384 + k];
    WrPk[idx] = packbf(w0, w1);
}

// Concatenated gPre weights/bias: gw[l][o<2304][k<384], gb[l][o]
__global__ void gpre_prep(const float* __restrict__ cwi, const float* __restrict__ pwh,
                          const float* __restrict__ cbi, const float* __restrict__ pbh,
                          float* __restrict__ gw, float* __restrict__ gb_)
{
    int idx = blockIdx.x * 256 + threadIdx.x;  // < 1769472
    int l = idx / 884736;
    int r = idx % 884736;
    int o = r / 384, k = r % 384;
    gw[idx] = (o < 1152) ? cwi[l * 442368 + o * 384 + k]
                         : pwh[l * 442368 + (o - 1152) * 384 + k];
    if (k == 0)
        gb_[l * 2304 + o] = (o < 1152) ? cbi[l * 1152 + o] : pbh[l * 1152 + o - 1152];
}

// q[row] = dot(Hc[row, hin:hin+384], wq)
__global__ __launch_bounds__(256)
void qpre_k(const float* __restrict__ Hc, int hin, const float* __restrict__ wq,
            float* __restrict__ q)
{
    int wave = threadIdx.x >> 6, lane = threadIdx.x & 63;
    int row = blockIdx.x * 4 + wave;   // < 1280
    const float* hp = Hc + row * LDH + hin;
    float s = 0.f;
#pragma unroll
    for (int u = 0; u < 6; ++u) s = fmaf(hp[lane + 64 * u], wq[lane + 64 * u], s);
#pragma unroll
    for (int m = 1; m < 64; m <<= 1) s += __shfl_xor(s, m);
    if (lane == 0) q[row] = s;
}

// ---- exchange primitives: 8B aligned relaxed agent-scope atomics ONLY ----
// payload in lo 32 bits, sequence tag in hi 32 bits: arrival IS detection.
#define ALD64(p)    __hip_atomic_load((p), __ATOMIC_RELAXED, __HIP_MEMORY_SCOPE_AGENT)
#define AST64(p, v) __hip_atomic_store((p), (v), __ATOMIC_RELAXED, __HIP_MEMORY_SCOPE_AGENT)

// ---------------------------------------------------------------------------
// Sliced scan v10: 256 WGs = 16 b x 16 slices, 512 threads, weights in LDS.
// v9 protocol with: (1) barrier-free per-thread exact-seq spins,
// (2) 128B line-aligned per-producer X segments (no cross-producer line
// sharing), (3) bf16-packed h exchange (13 words = 1 line per producer).
// X1: [b][slot][g*32 + 0..23]  M f32 words.
// X2: [b][slot][g*16 + 0..11 h-pairs, 12 kv]  (pad to 16).
// ---------------------------------------------------------------------------
__global__ __launch_bounds__(512)
void scan10(float* Hc, int hin, int hout,
            const float* __restrict__ gPre,
            const uint* __restrict__ WrPkl,   // [16][384][24]
            const uint* __restrict__ WgPkl,   // [16][384][72]
            const float* __restrict__ qpre,
            const float* __restrict__ gatwl,
            const float* __restrict__ gatbl,
            const int* __restrict__ adj,
            const int* __restrict__ smask,
            const float* __restrict__ cbh,
            const float* __restrict__ pbi,
            u64* __restrict__ X1,             // [16 b][2 slot][512]
            u64* __restrict__ X2)             // [16 b][2 slot][256]
{
    const int wg = blockIdx.x;
    const int b = wg >> 4, g = wg & 15;
    const int t = threadIdx.x;

    extern __shared__ uint WgL[];    // [384][72] packed, 110592 B
    __shared__ uint WrL[384 * 25];   // padded stride 25
    __shared__ uint Pc16[NN][25];    // packed (P0,P1), padded
    __shared__ float kvS[NN];
    __shared__ float2 ws01[NN];
    __shared__ float Mv[DH_];
    __shared__ float uA[864];        // hrow[384] / gate partials / gp+x handoff
    __shared__ float gs[144];
    __shared__ float karr[16];

    {   // preload packed weights into LDS
        const uint* src = WgPkl + g * 27648;
        for (int idx = t; idx < 27648; idx += 512) WgL[idx] = src[idx];
        const uint* src2 = WrPkl + g * 9216;
        for (int idx = t; idx < 9216; idx += 512) {
            int k = idx / 24, dl = idx % 24;
            WrL[k * 25 + dl] = src2[idx];
        }
    }
    __syncthreads();

    u64* X1b = X1 + b * 1024;    // 2 slots x 512
    u64* X2b = X2 + b * 512;     // 2 slots x 256
    const float gb = gatbl[0];

    // softmax-input prefetch registers (wave 0): current + next step
    int ca0 = 0, cs0 = 0, ca1 = 0, cs1 = 0;
    float cq = 0.f;
    int na0 = 0, ns0 = 0, na1 = 0, ns1 = 0;
    float nq = 0.f;

    // GRU-input prefetch registers
    float gpv = 0.f, xv = 0.f;

    for (int i = 0; i < NN; ++i) {
        const int rowi = b * NN + i;

        // ---- A. issue prefetches (registers; consumed later this step)
        if (t < 144) gpv = gPre[rowi * 2304 + (t / 24) * 384 + g * 24 + (t % 24)];
        else if (t < 168) xv = Hc[rowi * LDH + hin + g * 24 + (t - 144)];
        if (t < 64) {   // softmax inputs for step i+1
            int ip = (i + 1 < NN) ? (i + 1) : (NN - 1);
            int rp = b * NN + ip;
            na0 = adj[rp * NN + t];
            ns0 = smask[rp * NN + t];
            if (t + 64 < NN) { na1 = adj[rp * NN + t + 64]; ns1 = smask[rp * NN + t + 64]; }
            nq = qpre[rp];
        }
        // WAR guard: prior step's phase I readers of uA must finish before
        // this step's B writes uA (per-thread spins write immediately).
        __syncthreads();

        if (i > 0) {
            // ---- B. per-thread spin on X2 slot[(i-1)&1], exact seq == i
            const u64* Xs2 = X2b + ((i - 1) & 1) * 256;
            if (t < 256) {
                int gg = t >> 4, j = t & 15;
                if (j < 13) {
                    u64 w;
                    do { w = ALD64(&Xs2[gg * 16 + j]); } while ((uint)(w >> 32) != (uint)i);
                    uint lo = (uint)w;
                    if (j < 12) {
                        uA[gg * 24 + 2 * j]     = bflo(lo);
                        uA[gg * 24 + 2 * j + 1] = bfhi(lo);
                    } else {
                        karr[gg] = __uint_as_float(lo);
                    }
                }
            }
            __syncthreads();

            // ---- C. kv[i-1] scalar + P-update for row i-1 (LDS bf16 weights)
            if (t == 400) {
                float s = 0.f;
#pragma unroll
                for (int u = 0; u < 16; ++u) s += karr[u];
                kvS[i - 1] = s;
            }
            if (t < 384) {
                int dl0 = t >> 4, sub = t & 15, part = sub & 7, half = sub >> 3;
                float acc = 0.f;
#pragma unroll 8
                for (int m = 0; m < 48; ++m) {
                    int k = part + 8 * m;
                    uint u = WrL[k * 25 + dl0];
                    float w2_ = half ? bfhi(u) : bflo(u);
                    acc = fmaf(w2_, uA[k], acc);
                }
                acc += __shfl_xor(acc, 1);
                acc += __shfl_xor(acc, 2);
                acc += __shfl_xor(acc, 4);
                float other = __shfl_xor(acc, 8);
                if (sub == 0) Pc16[i - 1][dl0] = packbf(acc, other);
            }
            __syncthreads();

            // ---- D. masked softmax (wave 0) using prefetched inputs
            if (t < 64) {
                float q = cq + gb;
                int j0 = t, j1 = t + 64;
                float a0v = -1e30f, a1v = -1e30f;
                if (j0 < i && ca0 != 0) a0v = q + kvS[j0];
                if (j1 < i && ca1 != 0) a1v = q + kvS[j1];
                float mx = fmaxf(a0v, a1v);
#pragma unroll
                for (int m = 1; m < 64; m <<= 1) mx = fmaxf(mx, __shfl_xor(mx, m));
                float e0 = expf(a0v - mx);
                float e1 = (j1 < NN) ? expf(a1v - mx) : 0.f;
                float ss = e0 + e1;
#pragma unroll
                for (int m = 1; m < 64; m <<= 1) ss += __shfl_xor(ss, m);
                float inv = 1.f / ss;
                float w0 = e0 * inv;
                float s0 = (float)cs0;
                ws01[j0] = make_float2(w0 * s0, w0 - w0 * s0);
                if (j1 < NN) {
                    float w1 = e1 * inv;
                    float s1 = (float)cs1;
                    ws01[j1] = make_float2(w1 * s1, w1 - w1 * s1);
                }
            }
            __syncthreads();

            // ---- E. M slice -> own X1 segment (seq i+1; fire-and-forget)
            u64* Xs1 = X1b + (i & 1) * 512;
            if (t < 384) {
                int dl0 = t >> 4, sub = t & 15;
                float acc = 0.f;
                for (int j = sub; j < i; j += 16) {
                    uint u = Pc16[j][dl0];
                    float2 w2_ = ws01[j];
                    acc = fmaf(w2_.x, bflo(u), acc);
                    acc = fmaf(w2_.y, bfhi(u), acc);
                }
                acc += __shfl_xor(acc, 1);
                acc += __shfl_xor(acc, 2);
                acc += __shfl_xor(acc, 4);
                acc += __shfl_xor(acc, 8);
                if (sub == 0)
                    AST64(&Xs1[g * 32 + dl0],
                          ((u64)(uint)(i + 1) << 32) | (u64)__float_as_uint(acc));
            }

            // ---- F. per-thread spin for full M, exact seq == i+1
            if (t < 512) {
                int gg = t >> 5, j = t & 31;
                if (j < 24) {
                    u64 wm;
                    do { wm = ALD64(&Xs1[gg * 32 + j]); } while ((uint)(wm >> 32) != (uint)(i + 1));
                    Mv[gg * 24 + j] = __uint_as_float((uint)wm);
                }
            }
            __syncthreads();
        } else {
            if (t < 384) Mv[t] = 0.f;
            __syncthreads();
        }

        // rotate softmax prefetch registers (used at step i+1)
        if (t < 64) { ca0 = na0; cs0 = ns0; ca1 = na1; cs1 = ns1; cq = nq; }

        // ---- G. gate slice from LDS bf16: 144 outputs = 72 pairs x 6 k-chunks
        if (t < 432) {
            int cp = t % 72, kt = t / 72;
            int kbase = kt * 64;
            float a0 = 0.f, a1 = 0.f;
#pragma unroll 8
            for (int kk = 0; kk < 64; ++kk) {
                uint u = WgL[(kbase + kk) * 72 + cp];
                float m = Mv[kbase + kk];
                a0 = fmaf(bflo(u), m, a0);
                a1 = fmaf(bfhi(u), m, a1);
            }
            uA[kt * 144 + 2 * cp] = a0;
            uA[kt * 144 + 2 * cp + 1] = a1;
        }
        __syncthreads();
        if (t < 144) {
            float s = 0.f;
#pragma unroll
            for (int kt = 0; kt < 6; ++kt) s += uA[kt * 144 + t];
            gs[t] = s;
        }
        __syncthreads();

        // ---- H. hand off prefetched gp/x registers into (now free) uA
        if (t < 144) uA[t] = gpv;
        else if (t < 168) uA[t] = xv;
        __syncthreads();

        // ---- I. GRU cells for 24 dims -> Hc + own X2 segment (bf16 pairs)
        u64* Xs2w = X2b + (i & 1) * 256;
        if (t < 32) {
            float kp = 0.f, h = 0.f;
            if (t < 24) {
                int dg = g * 24 + t;
                float m = Mv[dg];
                float gir = uA[t], giz = uA[24 + t], gin = uA[48 + t];
                float ghr = gs[t] + cbh[dg];
                float ghz = gs[24 + t] + cbh[384 + dg];
                float ghn = gs[48 + t] + cbh[768 + dg];
                float r = 1.f / (1.f + expf(-(gir + ghr)));
                float z = 1.f / (1.f + expf(-(giz + ghz)));
                float n = tanhf(gin + r * ghn);
                float Cc = (1.f - z) * n + z * m;
                float pir = gs[72 + t] + pbi[dg];
                float piz = gs[96 + t] + pbi[384 + dg];
                float pin = gs[120 + t] + pbi[768 + dg];
                float phr = uA[72 + t], phz = uA[96 + t], phn = uA[120 + t];
                float r2 = 1.f / (1.f + expf(-(pir + phr)));
                float z2 = 1.f / (1.f + expf(-(piz + phz)));
                float n2 = tanhf(pin + r2 * phn);
                float x = uA[144 + t];
                float Pp = (1.f - z2) * n2 + z2 * x;
                h = Cc + Pp;
                Hc[rowi * LDH + hout + dg] = h;      // exact f32 for next stage
                kp = h * gatwl[384 + dg];
            }
            // pack h pairs via in-wave shuffle (sources = lanes 0..23, active)
            int src = (t < 12) ? 2 * t : 0;
            float ha = __shfl(h, src);
            float hb = __shfl(h, src + 1);
            if (t < 12)
                AST64(&Xs2w[g * 16 + t],
                      ((u64)(uint)(i + 1) << 32) | (u64)packbf(ha, hb));
#pragma unroll
            for (int m = 16; m >= 1; m >>= 1) kp += __shfl_down(kp, m);
            if (t == 0)
                AST64(&Xs2w[g * 16 + 12],
                      ((u64)(uint)(i + 1) << 32) | (u64)__float_as_uint(kp));
        }
        // no trailing barrier: loop-top barrier orders uA reuse; spins order X.
    }
}

// logits (7) + log_softmax, one wave per row
__global__ __launch_bounds__(256)
void mlp_final(const float* __restrict__ h, const float* __restrict__ w2,
               const float* __restrict__ b2, float* __restrict__ out)
{
    int wave = threadIdx.x >> 6, lane = threadIdx.x & 63;
    int r = blockIdx.x * 4 + wave;   // < 1280
    float hreg[6];
#pragma unroll
    for (int m = 0; m < 6; ++m) hreg[m] = h[r * 384 + lane + 64 * m];
    float logit[7];
#pragma unroll
    for (int c = 0; c < 7; ++c) {
        float s = 0.f;
#pragma unroll
        for (int m = 0; m < 6; ++m)
            s = fmaf(hreg[m], w2[c * 384 + lane + 64 * m], s);
#pragma unroll
        for (int m = 1; m < 64; m <<= 1) s += __shfl_xor(s, m);
        logit[c] = s + b2[c];
    }
    float mx = logit[0];
#pragma unroll
    for (int c = 1; c < 7; ++c) mx = fmaxf(mx, logit[c]);
    float se = 0.f;
#pragma unroll
    for (int c = 0; c < 7; ++c) se += expf(logit[c] - mx);
    float lse = mx + logf(se);
    if (lane < 7) out[r * 7 + lane] = logit[lane] - lse;
}

extern "C" void kernel_launch(void* const* d_in, const int* in_sizes, int n_in,
                              void* d_out, int out_size, void* d_ws, size_t ws_size,
                              hipStream_t stream)
{
    const float* ftext = (const float*)d_in[0];
    const float* faud  = (const float*)d_in[1];
    const int*   adj   = (const int*)d_in[2];
    const int*   smask = (const int*)d_in[3];
    const float* U1    = (const float*)d_in[6];
    const float* U2    = (const float*)d_in[7];
    const float* Pw    = (const float*)d_in[8];
    const float* Pb    = (const float*)d_in[9];
    const float* V1    = (const float*)d_in[10];
    const float* V2    = (const float*)d_in[11];
    const float* fc1w  = (const float*)d_in[12];
    const float* fc1b  = (const float*)d_in[13];
    const float* gatw  = (const float*)d_in[14];
    const float* gatb  = (const float*)d_in[15];
    const float* Wr0   = (const float*)d_in[16];
    const float* Wr1   = (const float*)d_in[17];
    const float* cwi   = (const float*)d_in[18];
    const float* cwh   = (const float*)d_in[19];
    const float* cbi   = (const float*)d_in[20];
    const float* cbh   = (const float*)d_in[21];
    const float* pwi   = (const float*)d_in[22];
    const float* pwh   = (const float*)d_in[23];
    const float* pbi   = (const float*)d_in[24];
    const float* pbh   = (const float*)d_in[25];
    const float* w0    = (const float*)d_in[26];
    const float* b0    = (const float*)d_in[27];
    const float* w1    = (const float*)d_in[28];
    const float* b1    = (const float*)d_in[29];
    const float* w2    = (const float*)d_in[30];
    const float* b2    = (const float*)d_in[31];
    float* out = (float*)d_out;
    float* ws = (float*)d_ws;

    // workspace layout (f32 words)
    float* Hcat  = ws;                        // 2,129,920
    float* gPre  = Hcat + 2129920;            // 2,949,120 (front: T1|T2; back: h2)
    float* T1b   = gPre;                      // 1,310,720
    float* T2b   = gPre + 1310720;            // 1,310,720
    float* CBuf  = gPre + 2949120;            // 655,360 (later h1)
    uint*  WgPk  = (uint*)(CBuf + 655360);    // 884,736
    uint*  WrPk  = WgPk + 884736;             // 294,912
    float* gw    = (float*)(WrPk + 294912);   // 1,769,472
    float* gb_   = gw + 1769472;              // 4,608
    float* qpreB = gb_ + 4608;                // 2,560
    u64*   X1l0  = (u64*)(qpreB + 2560);      // 16,384 u64 (16 b x 2 x 512)
    u64*   X2l0  = X1l0 + 16384;              //  8,192 u64 (16 b x 2 x 256)
    u64*   X1l1  = X2l0 + 8192;               // 16,384 u64
    u64*   X2l1  = X1l1 + 16384;              //  8,192 u64

    dim3 blk(256);
    auto gemm = [&](const float* A, int lda, const float* W, const float* Wb, int ldw,
                    const float* bias, float* C, int ldc, int K, int O,
                    int act, int accum) {
        dim3 grid(O / 64, 1280 / 64);
        gemm64<<<grid, blk, 0, stream>>>(A, lda, W, Wb, ldw, bias, C, ldc, K, act, accum);
    };

    // zero ALL exchange words each launch (kills cross-launch seq aliasing)
    hipMemsetAsync(X1l0, 0, (size_t)(16384 + 8192) * 2 * sizeof(u64), stream);

    // weight prep (independent of front-end)
    trans_wg3<<<3456, 256, 0, stream>>>(cwh, pwi, WgPk);
    trans_wr3<<<1152, 256, 0, stream>>>(Wr0, Wr1, WrPk);
    gpre_prep<<<6912, 256, 0, stream>>>(cwi, pwh, cbi, pbh, gw, gb_);

    // Front-end fusion: T1 = [sig(text@U1^T) | text@V1^T], T2 = [sig(aud@U2^T) | aud@V2^T]
    gemm(ftext, 1024, U1, V1, 1024, nullptr, T1b, 1024, 1024, 1024, 3, 0);
    gemm(faud,  512,  U2, V2, 512,  nullptr, T2b, 1024, 512,  1024, 3, 0);
    ew2<<<2560, 256, 0, stream>>>(T1b, T2b, CBuf, Hcat);
    gemm(CBuf, 512, Pw, nullptr, 512, Pb, Hcat + 1152, LDH, 512, 512, 0, 1);     // fused
    gemm(Hcat + 1152, LDH, fc1w, nullptr, 512, fc1b, Hcat, LDH, 512, 384, 1, 0); // H0

    // Two GAT/GRU layers
    for (int l = 0; l < 2; ++l) {
        gemm(Hcat + l * 384, LDH, gw + l * 884736, nullptr, 384, gb_ + l * 2304,
             gPre, 2304, 384, 2304, 0, 0);
        qpre_k<<<320, 256, 0, stream>>>(Hcat, l * 384, gatw + l * 768, qpreB + l * 1280);
        scan10<<<256, 512, 110592, stream>>>(Hcat, l * 384, (l + 1) * 384, gPre,
                                             WrPk + l * 147456, WgPk + l * 442368,
                                             qpreB + l * 1280, gatw + l * 768, gatb + l,
                                             adj, smask, cbh + l * 1152, pbi + l * 1152,
                                             l ? X1l1 : X1l0, l ? X2l1 : X2l0);
    }

    // Back-end MLP + log_softmax
    gemm(Hcat, LDH, w0, nullptr, LDH, b0, CBuf, 384, 1664, 384, 1, 0);   // h1
    gemm(CBuf, 384, w1, nullptr, 384, b1, gPre, 384, 384, 384, 1, 0);    // h2
    mlp_final<<<320, 256, 0, stream>>>(gPre, w2, b2, out);
}

// Round 11
// 1154.958 us; speedup vs baseline: 7.6964x; 1.1989x over previous
//
#include <hip/hip_runtime.h>
#include <hip/hip_bf16.h>
#include <math.h>

// Problem constants
#define BB 16
#define NN 80
#define DH_ 384
#define LDH 1664   // Hcat row stride: [H0 | H1 | H2 | fused]

typedef unsigned int uint;
typedef unsigned long long u64;
typedef __attribute__((ext_vector_type(8))) short short8;
typedef __attribute__((ext_vector_type(4))) float f32x4;

// ---- bf16 pack helpers (RNE) ----
__device__ __forceinline__ uint packbf(float lo, float hi)
{
    uint a = __float_as_uint(lo);
    a = (a + 0x7fffu + ((a >> 16) & 1u)) >> 16;
    uint b = __float_as_uint(hi);
    b = (b + 0x7fffu + ((b >> 16) & 1u)) & 0xffff0000u;
    return a | b;
}
__device__ __forceinline__ float bflo(uint u) { return __uint_as_float(u << 16); }
__device__ __forceinline__ float bfhi(uint u) { return __uint_as_float(u & 0xffff0000u); }
__device__ __forceinline__ unsigned short cvt1(float f)
{
    uint a = __float_as_uint(f);
    return (unsigned short)((a + 0x7fffu + ((a >> 16) & 1u)) >> 16);
}

// ---------------------------------------------------------------------------
// bf16 MFMA GEMM: C[r,o] = act(sum_k A[r,k]*W[o,k] + bias[o] (+C)).
// 64x64 tile, BK=64, 256 thr / 4 waves; wave w owns rows [w*16,+16).
// A: f32, converted to bf16 at staging. W: pre-converted bf16 [N][K].
// LDS 16B-chunk XOR swizzle (chunk ^= row&7) keeps frag ds_read_b128 ~free.
// mfma_f32_16x16x32_bf16 layouts: A row=lane&15,k=8*(lane>>4)+j;
// B col=lane&15,k=same; D col=lane&15,row=4*(lane>>4)+reg (m89-verified).
// act: 0 none, 1 relu, 2 sigmoid, 3 sigmoid for col<512 else none.
// ---------------------------------------------------------------------------
__global__ __launch_bounds__(256)
void gemm_mfma(const float* __restrict__ A, int lda,
               const unsigned short* __restrict__ W, int ldw,
               const float* __restrict__ bias,
               float* __restrict__ C, int ldc,
               int K, int act, int accum)
{
    __shared__ __attribute__((aligned(16))) unsigned short As[4096];
    __shared__ __attribute__((aligned(16))) unsigned short Bs[4096];
    const int t = threadIdx.x;
    const int lane = t & 63, wave = t >> 6;
    const int r0 = blockIdx.y * 64, o0 = blockIdx.x * 64;

    f32x4 acc0 = {0.f, 0.f, 0.f, 0.f};
    f32x4 acc1 = acc0, acc2 = acc0, acc3 = acc0;

    const int srow = t >> 2;                 // 0..63
    const int scp = (t & 3) * 2;             // chunk pair 0,2,4,6
    const int sw0 = ((scp ^ (srow & 7))) * 8;
    const int sw1 = (((scp + 1) ^ (srow & 7))) * 8;
    const float* ap0 = A + (size_t)(r0 + srow) * lda + scp * 8;
    const unsigned short* bp0 = W + (size_t)(o0 + srow) * ldw + scp * 8;

    const int fr = lane & 15, kg = lane >> 4;
    const int fsw = fr & 7;
    const int arow = (wave * 16 + fr) * 64;

    for (int kb = 0; kb < K; kb += 64) {
        float4 a0 = *(const float4*)(ap0 + kb);
        float4 a1 = *(const float4*)(ap0 + kb + 4);
        float4 a2 = *(const float4*)(ap0 + kb + 8);
        float4 a3 = *(const float4*)(ap0 + kb + 12);
        uint4 b0 = *(const uint4*)(bp0 + kb);
        uint4 b1 = *(const uint4*)(bp0 + kb + 8);
        uint4 apk0, apk1;
        apk0.x = packbf(a0.x, a0.y); apk0.y = packbf(a0.z, a0.w);
        apk0.z = packbf(a1.x, a1.y); apk0.w = packbf(a1.z, a1.w);
        apk1.x = packbf(a2.x, a2.y); apk1.y = packbf(a2.z, a2.w);
        apk1.z = packbf(a3.x, a3.y); apk1.w = packbf(a3.z, a3.w);
        *(uint4*)&As[srow * 64 + sw0] = apk0;
        *(uint4*)&As[srow * 64 + sw1] = apk1;
        *(uint4*)&Bs[srow * 64 + sw0] = b0;
        *(uint4*)&Bs[srow * 64 + sw1] = b1;
        __syncthreads();
#pragma unroll
        for (int h = 0; h < 2; ++h) {
            int ach = kg + 4 * h;
            short8 af = *(const short8*)&As[arow + ((ach ^ fsw)) * 8];
            short8 bf0 = *(const short8*)&Bs[(0 * 16 + fr) * 64 + ((ach ^ fsw)) * 8];
            short8 bf1 = *(const short8*)&Bs[(1 * 16 + fr) * 64 + ((ach ^ fsw)) * 8];
            short8 bf2 = *(const short8*)&Bs[(2 * 16 + fr) * 64 + ((ach ^ fsw)) * 8];
            short8 bf3 = *(const short8*)&Bs[(3 * 16 + fr) * 64 + ((ach ^ fsw)) * 8];
            acc0 = __builtin_amdgcn_mfma_f32_16x16x32_bf16(af, bf0, acc0, 0, 0, 0);
            acc1 = __builtin_amdgcn_mfma_f32_16x16x32_bf16(af, bf1, acc1, 0, 0, 0);
            acc2 = __builtin_amdgcn_mfma_f32_16x16x32_bf16(af, bf2, acc2, 0, 0, 0);
            acc3 = __builtin_amdgcn_mfma_f32_16x16x32_bf16(af, bf3, acc3, 0, 0, 0);
        }
        __syncthreads();
    }
    const int rg = lane >> 4;
    f32x4 av[4] = {acc0, acc1, acc2, acc3};
#pragma unroll
    for (int c = 0; c < 4; ++c) {
        int col = o0 + c * 16 + fr;
        float bv = bias ? bias[col] : 0.f;
#pragma unroll
        for (int r = 0; r < 4; ++r) {
            int row = r0 + wave * 16 + rg * 4 + r;
            float v = av[c][r] + bv;
            if (accum) v += C[(size_t)row * ldc + col];
            if (act == 1) v = fmaxf(v, 0.f);
            else if (act == 2) v = 1.f / (1.f + expf(-v));
            else if (act == 3 && col < 512) v = 1.f / (1.f + expf(-v));
            C[(size_t)row * ldc + col] = v;
        }
    }
}

// Convert all GEMM weights to one bf16 buffer (+ gPre bias extraction).
// Layout (u16 offsets): UV1@0[1024][1024], UV2@1048576[1024][512],
// Pw@1572864[512][512], fc1@1835008[384][512], gw@2031616[2][2304][384]
// ([cwi_l|pwh_l]), w0@3801088[384][1664], w1@4440064[384][384].
__global__ void wcvt(const float* __restrict__ U1, const float* __restrict__ V1,
                     const float* __restrict__ U2, const float* __restrict__ V2,
                     const float* __restrict__ Pw, const float* __restrict__ fc1w,
                     const float* __restrict__ cwi, const float* __restrict__ pwh,
                     const float* __restrict__ w0, const float* __restrict__ w1,
                     const float* __restrict__ cbi, const float* __restrict__ pbh,
                     unsigned short* __restrict__ wB, float* __restrict__ gb_)
{
    int idx = blockIdx.x * 256 + threadIdx.x;
    if (idx < 4587520) {
        float v;
        if      (idx < 524288)  v = U1[idx];
        else if (idx < 1048576) v = V1[idx - 524288];
        else if (idx < 1310720) v = U2[idx - 1048576];
        else if (idx < 1572864) v = V2[idx - 1310720];
        else if (idx < 1835008) v = Pw[idx - 1572864];
        else if (idx < 2031616) v = fc1w[idx - 1835008];
        else if (idx < 2473984) v = cwi[idx - 2031616];
        else if (idx < 2916352) v = pwh[idx - 2473984];
        else if (idx < 3358720) v = cwi[442368 + idx - 2916352];
        else if (idx < 3801088) v = pwh[442368 + idx - 3358720];
        else if (idx < 4440064) v = w0[idx - 3801088];
        else                    v = w1[idx - 4440064];
        wB[idx] = cvt1(v);
    } else if (idx < 4592128) {
        int j = idx - 4587520;
        int l = j / 2304, o = j % 2304;
        gb_[j] = (o < 1152) ? cbi[l * 1152 + o] : pbh[l * 1152 + o - 1152];
    }
}

// c_ = T1[:, :512]*T2[:, :512] -> CBuf ; Hcat fused col = V1+V2 partial sums
__global__ void ew2(const float* __restrict__ T1, const float* __restrict__ T2,
                    float* __restrict__ CBuf, float* __restrict__ Hc)
{
    int idx = blockIdx.x * 256 + threadIdx.x;  // < 655360
    int r = idx >> 9, c = idx & 511;
    CBuf[idx] = T1[r * 1024 + c] * T2[r * 1024 + c];
    Hc[r * LDH + 1152 + c] = T1[r * 1024 + 512 + c] + T2[r * 1024 + 512 + c];
}

// WgPk[l][g][k=384][cp=72]: packed bf16 pair for gate cols c=2cp, 2cp+1
__global__ void trans_wg3(const float* __restrict__ cwh, const float* __restrict__ pwi,
                          uint* __restrict__ WgPk)
{
    int idx = blockIdx.x * 256 + threadIdx.x;  // < 884736
    int l = idx / 442368;
    int r = idx % 442368;
    int g = r / 27648;
    int r2 = r % 27648;
    int k = r2 / 72, cp = r2 % 72;
    float v[2];
#pragma unroll
    for (int u = 0; u < 2; ++u) {
        int c = 2 * cp + u;
        int idx6 = c / 24, o = c % 24, d = g * 24 + o;
        v[u] = (idx6 < 3) ? cwh[l * 442368 + (idx6 * 384 + d) * 384 + k]
                          : pwi[l * 442368 + ((idx6 - 3) * 384 + d) * 384 + k];
    }
    WgPk[idx] = packbf(v[0], v[1]);
}

// WrPk[l][g][k=384][dl=24]: packed bf16 (Wr0[g*24+dl][k], Wr1[g*24+dl][k])
__global__ void trans_wr3(const float* __restrict__ Wr0, const float* __restrict__ Wr1,
                          uint* __restrict__ WrPk)
{
    int idx = blockIdx.x * 256 + threadIdx.x;  // < 294912
    int l = idx / 147456;
    int r = idx % 147456;
    int g = r / 9216;
    int r2 = r % 9216;
    int k = r2 / 24, dl = r2 % 24;
    int row = g * 24 + dl;
    float w0 = Wr0[l * 147456 + row * 384 + k];
    float w1 = Wr1[l * 147456 + row * 384 + k];
    WrPk[idx] = packbf(w0, w1);
}

// q[row] = dot(Hc[row, hin:hin+384], wq)
__global__ __launch_bounds__(256)
void qpre_k(const float* __restrict__ Hc, int hin, const float* __restrict__ wq,
            float* __restrict__ q)
{
    int wave = threadIdx.x >> 6, lane = threadIdx.x & 63;
    int row = blockIdx.x * 4 + wave;   // < 1280
    const float* hp = Hc + row * LDH + hin;
    float s = 0.f;
#pragma unroll
    for (int u = 0; u < 6; ++u) s = fmaf(hp[lane + 64 * u], wq[lane + 64 * u], s);
#pragma unroll
    for (int m = 1; m < 64; m <<= 1) s += __shfl_xor(s, m);
    if (lane == 0) q[row] = s;
}

// ---- exchange primitives: 8B aligned relaxed agent-scope atomics ONLY ----
#define ALD64(p)    __hip_atomic_load((p), __ATOMIC_RELAXED, __HIP_MEMORY_SCOPE_AGENT)
#define AST64(p, v) __hip_atomic_store((p), (v), __ATOMIC_RELAXED, __HIP_MEMORY_SCOPE_AGENT)

// ---------------------------------------------------------------------------
// Sliced scan v10 (unchanged from round 10 — proven at 508 us/dispatch).
// ---------------------------------------------------------------------------
__global__ __launch_bounds__(512)
void scan10(float* Hc, int hin, int hout,
            const float* __restrict__ gPre,
            const uint* __restrict__ WrPkl,   // [16][384][24]
            const uint* __restrict__ WgPkl,   // [16][384][72]
            const float* __restrict__ qpre,
            const float* __restrict__ gatwl,
            const float* __restrict__ gatbl,
            const int* __restrict__ adj,
            const int* __restrict__ smask,
            const float* __restrict__ cbh,
            const float* __restrict__ pbi,
            u64* __restrict__ X1,             // [16 b][2 slot][512]
            u64* __restrict__ X2)             // [16 b][2 slot][256]
{
    const int wg = blockIdx.x;
    const int b = wg >> 4, g = wg & 15;
    const int t = threadIdx.x;

    extern __shared__ uint WgL[];    // [384][72] packed, 110592 B
    __shared__ uint WrL[384 * 25];   // padded stride 25
    __shared__ uint Pc16[NN][25];    // packed (P0,P1), padded
    __shared__ float kvS[NN];
    __shared__ float2 ws01[NN];
    __shared__ float Mv[DH_];
    __shared__ float uA[864];        // hrow[384] / gate partials / gp+x handoff
    __shared__ float gs[144];
    __shared__ float karr[16];

    {   // preload packed weights into LDS
        const uint* src = WgPkl + g * 27648;
        for (int idx = t; idx < 27648; idx += 512) WgL[idx] = src[idx];
        const uint* src2 = WrPkl + g * 9216;
        for (int idx = t; idx < 9216; idx += 512) {
            int k = idx / 24, dl = idx % 24;
            WrL[k * 25 + dl] = src2[idx];
        }
    }
    __syncthreads();

    u64* X1b = X1 + b * 1024;    // 2 slots x 512
    u64* X2b = X2 + b * 512;     // 2 slots x 256
    const float gb = gatbl[0];

    int ca0 = 0, cs0 = 0, ca1 = 0, cs1 = 0;
    float cq = 0.f;
    int na0 = 0, ns0 = 0, na1 = 0, ns1 = 0;
    float nq = 0.f;
    float gpv = 0.f, xv = 0.f;

    for (int i = 0; i < NN; ++i) {
        const int rowi = b * NN + i;

        // ---- A. issue prefetches (registers; consumed later this step)
        if (t < 144) gpv = gPre[rowi * 2304 + (t / 24) * 384 + g * 24 + (t % 24)];
        else if (t < 168) xv = Hc[rowi * LDH + hin + g * 24 + (t - 144)];
        if (t < 64) {
            int ip = (i + 1 < NN) ? (i + 1) : (NN - 1);
            int rp = b * NN + ip;
            na0 = adj[rp * NN + t];
            ns0 = smask[rp * NN + t];
            if (t + 64 < NN) { na1 = adj[rp * NN + t + 64]; ns1 = smask[rp * NN + t + 64]; }
            nq = qpre[rp];
        }
        __syncthreads();

        if (i > 0) {
            // ---- B. per-thread spin on X2 slot[(i-1)&1], exact seq == i
            const u64* Xs2 = X2b + ((i - 1) & 1) * 256;
            if (t < 256) {
                int gg = t >> 4, j = t & 15;
                if (j < 13) {
                    u64 w;
                    do { w = ALD64(&Xs2[gg * 16 + j]); } while ((uint)(w >> 32) != (uint)i);
                    uint lo = (uint)w;
                    if (j < 12) {
                        uA[gg * 24 + 2 * j]     = bflo(lo);
                        uA[gg * 24 + 2 * j + 1] = bfhi(lo);
                    } else {
                        karr[gg] = __uint_as_float(lo);
                    }
                }
            }
            __syncthreads();

            // ---- C. kv[i-1] scalar + P-update for row i-1 (LDS bf16 weights)
            if (t == 400) {
                float s = 0.f;
#pragma unroll
                for (int u = 0; u < 16; ++u) s += karr[u];
                kvS[i - 1] = s;
            }
            if (t < 384) {
                int dl0 = t >> 4, sub = t & 15, part = sub & 7, half = sub >> 3;
                float acc = 0.f;
#pragma unroll 8
                for (int m = 0; m < 48; ++m) {
                    int k = part + 8 * m;
                    uint u = WrL[k * 25 + dl0];
                    float w2_ = half ? bfhi(u) : bflo(u);
                    acc = fmaf(w2_, uA[k], acc);
                }
                acc += __shfl_xor(acc, 1);
                acc += __shfl_xor(acc, 2);
                acc += __shfl_xor(acc, 4);
                float other = __shfl_xor(acc, 8);
                if (sub == 0) Pc16[i - 1][dl0] = packbf(acc, other);
            }
            __syncthreads();

            // ---- D. masked softmax (wave 0) using prefetched inputs
            if (t < 64) {
                float q = cq + gb;
                int j0 = t, j1 = t + 64;
                float a0v = -1e30f, a1v = -1e30f;
                if (j0 < i && ca0 != 0) a0v = q + kvS[j0];
                if (j1 < i && ca1 != 0) a1v = q + kvS[j1];
                float mx = fmaxf(a0v, a1v);
#pragma unroll
                for (int m = 1; m < 64; m <<= 1) mx = fmaxf(mx, __shfl_xor(mx, m));
                float e0 = expf(a0v - mx);
                float e1 = (j1 < NN) ? expf(a1v - mx) : 0.f;
                float ss = e0 + e1;
#pragma unroll
                for (int m = 1; m < 64; m <<= 1) ss += __shfl_xor(ss, m);
                float inv = 1.f / ss;
                float w0 = e0 * inv;
                float s0 = (float)cs0;
                ws01[j0] = make_float2(w0 * s0, w0 - w0 * s0);
                if (j1 < NN) {
                    float w1 = e1 * inv;
                    float s1 = (float)cs1;
                    ws01[j1] = make_float2(w1 * s1, w1 - w1 * s1);
                }
            }
            __syncthreads();

            // ---- E. M slice -> own X1 segment (seq i+1; fire-and-forget)
            u64* Xs1 = X1b + (i & 1) * 512;
            if (t < 384) {
                int dl0 = t >> 4, sub = t & 15;
                float acc = 0.f;
                for (int j = sub; j < i; j += 16) {
                    uint u = Pc16[j][dl0];
                    float2 w2_ = ws01[j];
                    acc = fmaf(w2_.x, bflo(u), acc);
                    acc = fmaf(w2_.y, bfhi(u), acc);
                }
                acc += __shfl_xor(acc, 1);
                acc += __shfl_xor(acc, 2);
                acc += __shfl_xor(acc, 4);
                acc += __shfl_xor(acc, 8);
                if (sub == 0)
                    AST64(&Xs1[g * 32 + dl0],
                          ((u64)(uint)(i + 1) << 32) | (u64)__float_as_uint(acc));
            }

            // ---- F. per-thread spin for full M, exact seq == i+1
            if (t < 512) {
                int gg = t >> 5, j = t & 31;
                if (j < 24) {
                    u64 wm;
                    do { wm = ALD64(&Xs1[gg * 32 + j]); } while ((uint)(wm >> 32) != (uint)(i + 1));
                    Mv[gg * 24 + j] = __uint_as_float((uint)wm);
                }
            }
            __syncthreads();
        } else {
            if (t < 384) Mv[t] = 0.f;
            __syncthreads();
        }

        if (t < 64) { ca0 = na0; cs0 = ns0; ca1 = na1; cs1 = ns1; cq = nq; }

        // ---- G. gate slice from LDS bf16: 144 outputs = 72 pairs x 6 k-chunks
        if (t < 432) {
            int cp = t % 72, kt = t / 72;
            int kbase = kt * 64;
            float a0 = 0.f, a1 = 0.f;
#pragma unroll 8
            for (int kk = 0; kk < 64; ++kk) {
                uint u = WgL[(kbase + kk) * 72 + cp];
                float m = Mv[kbase + kk];
                a0 = fmaf(bflo(u), m, a0);
                a1 = fmaf(bfhi(u), m, a1);
            }
            uA[kt * 144 + 2 * cp] = a0;
            uA[kt * 144 + 2 * cp + 1] = a1;
        }
        __syncthreads();
        if (t < 144) {
            float s = 0.f;
#pragma unroll
            for (int kt = 0; kt < 6; ++kt) s += uA[kt * 144 + t];
            gs[t] = s;
        }
        __syncthreads();

        // ---- H. hand off prefetched gp/x registers into (now free) uA
        if (t < 144) uA[t] = gpv;
        else if (t < 168) uA[t] = xv;
        __syncthreads();

        // ---- I. GRU cells for 24 dims -> Hc + own X2 segment (bf16 pairs)
        u64* Xs2w = X2b + (i & 1) * 256;
        if (t < 32) {
            float kp = 0.f, h = 0.f;
            if (t < 24) {
                int dg = g * 24 + t;
                float m = Mv[dg];
                float gir = uA[t], giz = uA[24 + t], gin = uA[48 + t];
                float ghr = gs[t] + cbh[dg];
                float ghz = gs[24 + t] + cbh[384 + dg];
                float ghn = gs[48 + t] + cbh[768 + dg];
                float r = 1.f / (1.f + expf(-(gir + ghr)));
                float z = 1.f / (1.f + expf(-(giz + ghz)));
                float n = tanhf(gin + r * ghn);
                float Cc = (1.f - z) * n + z * m;
                float pir = gs[72 + t] + pbi[dg];
                float piz = gs[96 + t] + pbi[384 + dg];
                float pin = gs[120 + t] + pbi[768 + dg];
                float phr = uA[72 + t], phz = uA[96 + t], phn = uA[120 + t];
                float r2 = 1.f / (1.f + expf(-(pir + phr)));
                float z2 = 1.f / (1.f + expf(-(piz + phz)));
                float n2 = tanhf(pin + r2 * phn);
                float x = uA[144 + t];
                float Pp = (1.f - z2) * n2 + z2 * x;
                h = Cc + Pp;
                Hc[rowi * LDH + hout + dg] = h;
                kp = h * gatwl[384 + dg];
            }
            int src = (t < 12) ? 2 * t : 0;
            float ha = __shfl(h, src);
            float hb = __shfl(h, src + 1);
            if (t < 12)
                AST64(&Xs2w[g * 16 + t],
                      ((u64)(uint)(i + 1) << 32) | (u64)packbf(ha, hb));
#pragma unroll
            for (int m = 16; m >= 1; m >>= 1) kp += __shfl_down(kp, m);
            if (t == 0)
                AST64(&Xs2w[g * 16 + 12],
                      ((u64)(uint)(i + 1) << 32) | (u64)__float_as_uint(kp));
        }
    }
}

// logits (7) + log_softmax, one wave per row
__global__ __launch_bounds__(256)
void mlp_final(const float* __restrict__ h, const float* __restrict__ w2,
               const float* __restrict__ b2, float* __restrict__ out)
{
    int wave = threadIdx.x >> 6, lane = threadIdx.x & 63;
    int r = blockIdx.x * 4 + wave;   // < 1280
    float hreg[6];
#pragma unroll
    for (int m = 0; m < 6; ++m) hreg[m] = h[r * 384 + lane + 64 * m];
    float logit[7];
#pragma unroll
    for (int c = 0; c < 7; ++c) {
        float s = 0.f;
#pragma unroll
        for (int m = 0; m < 6; ++m)
            s = fmaf(hreg[m], w2[c * 384 + lane + 64 * m], s);
#pragma unroll
        for (int m = 1; m < 64; m <<= 1) s += __shfl_xor(s, m);
        logit[c] = s + b2[c];
    }
    float mx = logit[0];
#pragma unroll
    for (int c = 1; c < 7; ++c) mx = fmaxf(mx, logit[c]);
    float se = 0.f;
#pragma unroll
    for (int c = 0; c < 7; ++c) se += expf(logit[c] - mx);
    float lse = mx + logf(se);
    if (lane < 7) out[r * 7 + lane] = logit[lane] - lse;
}

extern "C" void kernel_launch(void* const* d_in, const int* in_sizes, int n_in,
                              void* d_out, int out_size, void* d_ws, size_t ws_size,
                              hipStream_t stream)
{
    const float* ftext = (const float*)d_in[0];
    const float* faud  = (const float*)d_in[1];
    const int*   adj   = (const int*)d_in[2];
    const int*   smask = (const int*)d_in[3];
    const float* U1    = (const float*)d_in[6];
    const float* U2    = (const float*)d_in[7];
    const float* Pw    = (const float*)d_in[8];
    const float* Pb    = (const float*)d_in[9];
    const float* V1    = (const float*)d_in[10];
    const float* V2    = (const float*)d_in[11];
    const float* fc1w  = (const float*)d_in[12];
    const float* fc1b  = (const float*)d_in[13];
    const float* gatw  = (const float*)d_in[14];
    const float* gatb  = (const float*)d_in[15];
    const float* Wr0   = (const float*)d_in[16];
    const float* Wr1   = (const float*)d_in[17];
    const float* cwi   = (const float*)d_in[18];
    const float* cwh   = (const float*)d_in[19];
    const float* cbi   = (const float*)d_in[20];
    const float* cbh   = (const float*)d_in[21];
    const float* pwi   = (const float*)d_in[22];
    const float* pwh   = (const float*)d_in[23];
    const float* pbi   = (const float*)d_in[24];
    const float* pbh   = (const float*)d_in[25];
    const float* w0    = (const float*)d_in[26];
    const float* b0    = (const float*)d_in[27];
    const float* w1    = (const float*)d_in[28];
    const float* b1    = (const float*)d_in[29];
    const float* w2    = (const float*)d_in[30];
    const float* b2    = (const float*)d_in[31];
    float* out = (float*)d_out;
    float* ws = (float*)d_ws;

    // workspace layout (f32 words)
    float* Hcat  = ws;                        // 2,129,920
    float* gPre  = ws + 2129920;              // 2,949,120 (front: T1|T2; back: h2)
    float* T1b   = gPre;                      // 1,310,720
    float* T2b   = gPre + 1310720;            // 1,310,720
    float* CBuf  = ws + 5079040;              // 655,360 (later h1)
    uint*  WgPk  = (uint*)(ws + 5734400);     // 884,736 u32
    uint*  WrPk  = (uint*)(ws + 6619136);     // 294,912 u32
    float* gb_   = ws + 6914048;              // 4,608
    float* qpreB = ws + 6918656;              // 2,560
    u64*   X1l0  = (u64*)(ws + 6921216);      // 16,384 u64
    u64*   X2l0  = X1l0 + 16384;              //  8,192 u64
    u64*   X1l1  = X2l0 + 8192;               // 16,384 u64
    u64*   X2l1  = X1l1 + 16384;              //  8,192 u64
    unsigned short* wB = (unsigned short*)(ws + 7019520);  // 4,587,520 u16

    auto g = [&](const float* A, int lda, size_t woff, int ldw,
                 const float* bias, float* C, int ldc, int K, int N,
                 int act, int accum) {
        dim3 grid(N / 64, 1280 / 64);
        gemm_mfma<<<grid, 256, 0, stream>>>(A, lda, wB + woff, ldw, bias, C, ldc,
                                            K, act, accum);
    };

    // zero ALL exchange words each launch (kills cross-launch seq aliasing)
    hipMemsetAsync(X1l0, 0, (size_t)(16384 + 8192) * 2 * sizeof(u64), stream);

    // weight prep (independent of front-end)
    wcvt<<<17938, 256, 0, stream>>>(U1, V1, U2, V2, Pw, fc1w, cwi, pwh, w0, w1,
                                    cbi, pbh, wB, gb_);
    trans_wg3<<<3456, 256, 0, stream>>>(cwh, pwi, WgPk);
    trans_wr3<<<1152, 256, 0, stream>>>(Wr0, Wr1, WrPk);

    // Front-end fusion (bf16 MFMA): T1=[sig(text@U1^T)|text@V1^T], T2 likewise
    g(ftext, 1024, 0, 1024, nullptr, T1b, 1024, 1024, 1024, 3, 0);
    g(faud, 512, 1048576, 512, nullptr, T2b, 1024, 512, 1024, 3, 0);
    ew2<<<2560, 256, 0, stream>>>(T1b, T2b, CBuf, Hcat);
    g(CBuf, 512, 1572864, 512, Pb, Hcat + 1152, LDH, 512, 512, 0, 1);      // fused
    g(Hcat + 1152, LDH, 1835008, 512, fc1b, Hcat, LDH, 512, 384, 1, 0);    // H0

    // Two GAT/GRU layers (scan10 unchanged)
    for (int l = 0; l < 2; ++l) {
        g(Hcat + l * 384, LDH, 2031616 + (size_t)l * 884736, 384,
          gb_ + l * 2304, gPre, 2304, 384, 2304, 0, 0);
        qpre_k<<<320, 256, 0, stream>>>(Hcat, l * 384, gatw + l * 768, qpreB + l * 1280);
        scan10<<<256, 512, 110592, stream>>>(Hcat, l * 384, (l + 1) * 384, gPre,
                                             WrPk + l * 147456, WgPk + l * 442368,
                                             qpreB + l * 1280, gatw + l * 768, gatb + l,
                                             adj, smask, cbh + l * 1152, pbi + l * 1152,
                                             l ? X1l1 : X1l0, l ? X2l1 : X2l0);
    }

    // Back-end MLP + log_softmax (bf16 MFMA)
    g(Hcat, LDH, 3801088, 1664, b0, CBuf, 384, 1664, 384, 1, 0);   // h1
    g(CBuf, 384, 4440064, 384, b1, gPre, 384, 384, 384, 1, 0);     // h2
    mlp_final<<<320, 256, 0, stream>>>(gPre, w2, b2, out);
}